// Round 11
// baseline (420.928 us; speedup 1.0000x reference)
//
#include <hip/hip_runtime.h>
#include <math.h>

#define NN 128
#define FF 64
#define KK 50
#define PT 8
#define EPSV 1e-6f

// ws layout (floats):
// dws: [B*N*N]      off 0         (524288)
// T:   [B*N*N]      off 524288
// wu:  [3*50*64*2]  off 1048576
// C:   [B*N*3*64]   off 2097152
// Fr:  [B*N*3]      off 2883584

__device__ __forceinline__ float softplus_fast(float z) {
    float e = __expf(-fabsf(z));
    float l = __logf(1.f + e);
    return fmaxf(z, 0.f) + l;
}

__device__ __forceinline__ float rdlane(float v, int sel) {
    return __uint_as_float(__builtin_amdgcn_readlane(__float_as_uint(v), sel));
}

__global__ __launch_bounds__(256) void k_dist(const float* __restrict__ xs, float* __restrict__ dws)
{
    int tid = blockIdx.x * 256 + threadIdx.x;
    int b = tid >> 14;
    int rem = tid & 16383;
    int i = rem >> 7, a = rem & 127;
    const float* xb = xs + b * (NN * 3);
    float dx = xb[i*3+0] - xb[a*3+0];
    float dy = xb[i*3+1] - xb[a*3+1];
    float dz = xb[i*3+2] - xb[a*3+2];
    dws[tid] = sqrtf(dx*dx + dy*dy + dz*dz + EPSV);
}

// build (w, u) pairs for bwd: u[l][k][f] = 2*gamma*mu_k * W1l[k][f]
__global__ __launch_bounds__(256) void k_prep(
    const float* __restrict__ W1a, const float* __restrict__ W1b, const float* __restrict__ W1c,
    const float* __restrict__ mus, const float* __restrict__ gamma,
    float2* __restrict__ wu)
{
    int idx = blockIdx.x * 256 + threadIdx.x;   // 3*50*64 = 9600
    if (idx < 3 * KK * FF) {
        int l = idx / (KK * FF), r = idx - l * (KK * FF);
        int k = r >> 6;
        const float* W = (l == 0) ? W1a : (l == 1) ? W1b : W1c;
        float w = W[r];
        wu[idx] = make_float2(w, 2.f * gamma[0] * mus[k] * w);
    }
}

// ------- forward: rbf wave-uniform via readlane->SGPR, weights in LDS -------
__global__ __launch_bounds__(512, 2) void k_fwd(
    const float* __restrict__ dws,
    const float* __restrict__ mus, const float* __restrict__ gamma,
    const float* __restrict__ W1a, const float* __restrict__ W1b, const float* __restrict__ W1c,
    const float* __restrict__ b1a, const float* __restrict__ b1b, const float* __restrict__ b1c,
    const float* __restrict__ W2a, const float* __restrict__ W2b, const float* __restrict__ W2c,
    const float* __restrict__ b2a, const float* __restrict__ b2b, const float* __restrict__ b2c,
    const float* __restrict__ Wenc, const float* __restrict__ benc,
    const float* __restrict__ Wt1, const float* __restrict__ bt1, const float* __restrict__ Wt2,
    float* __restrict__ Cout)
{
    __shared__ float2 wab[KK * FF];       // (wa,wb)  25600 B
    __shared__ float  wcs[KK * FF];       // wc       12800 B
    __shared__ float  mus_s[64];
    __shared__ double epid[8][FF];
    __shared__ float  epif[8][FF];

    int tid = threadIdx.x;
    for (int idx = tid; idx < KK * FF; idx += 512) {
        wab[idx] = make_float2(W1a[idx], W1b[idx]);
        wcs[idx] = W1c[idx];
    }
    if (tid < 64) mus_s[tid] = (tid < KK) ? mus[tid] : 0.f;
    __syncthreads();

    int wave = tid >> 6, lane = tid & 63, f = lane;
    int atom = blockIdx.x * 8 + wave;
    int i = atom & 127;
    float gam = gamma[0];
    float bb0 = b1a[f], bb1 = b1b[f], bb2 = b1c[f];
    double us0 = 0.0, us1 = 0.0, us2 = 0.0;
    const float* drow = dws + (atom << 7);
    int pidx = lane & 15;      // this lane's pair slot
    int rsel = lane >> 4;      // this lane's k-residue

    #pragma unroll 1
    for (int t = 0; t < 8; ++t) {
        // d for this lane's pair slot, straight from global (L2-hit, 16-way bcast)
        float dval = drow[(i + 1 + 16 * t + pidx) & 127];
        // 13 rbf values per lane: lane 16*(k&3)+p holds group q=k>>2 (k=4q+rsel)
        float rl[13];
        #pragma unroll
        for (int q = 0; q < 13; ++q) {
            float dd = dval - mus_s[4 * q + rsel];
            rl[q] = __expf(-gam * dd * dd);
        }
        float z0[16], z1[16], z2[16];
        #pragma unroll
        for (int p = 0; p < 16; ++p) { z0[p] = bb0; z1[p] = bb1; z2[p] = bb2; }
        #pragma unroll
        for (int k = 0; k < KK; ++k) {
            float2 wv = wab[(k << 6) + f];
            float  wc = wcs[(k << 6) + f];
            float rq = rl[k >> 2];
            int   sb = (k & 3) << 4;
            #pragma unroll
            for (int p = 0; p < 16; ++p) {
                float rb = rdlane(rq, sb + p);   // SGPR broadcast
                z0[p] = fmaf(rb, wv.x, z0[p]);
                z1[p] = fmaf(rb, wv.y, z1[p]);
                z2[p] = fmaf(rb, wc,   z2[p]);
            }
        }
        int base = 16 * t;
        #pragma unroll
        for (int p = 0; p < 16; ++p) {
            if (base + p < 127) {
                us0 += (double)softplus_fast(z0[p]);
                us1 += (double)softplus_fast(z1[p]);
                us2 += (double)softplus_fast(z2[p]);
            }
        }
    }

    // per-atom epilogue (wave-local, double precision for h/pre path)
    double wf0, wf1, wf2;
    {
        epid[wave][lane] = us0;
        double acc = 0.0;
        for (int m = 0; m < 64; ++m) acc += epid[wave][m] * (double)W2a[m*64 + f];
        wf0 = 1.0 + acc + 127.0 * (double)b2a[f];

        epid[wave][lane] = us1;
        double acc1 = 0.0;
        for (int m = 0; m < 64; ++m) acc1 += epid[wave][m] * (double)W2b[m*64 + f];
        wf1 = 1.0 + acc1 + 127.0 * (double)b2b[f];

        epid[wave][lane] = us2;
        double acc2 = 0.0;
        for (int m = 0; m < 64; ++m) acc2 += epid[wave][m] * (double)W2c[m*64 + f];
        wf2 = 1.0 + acc2 + 127.0 * (double)b2c[f];
    }
    double h0 = (double)Wenc[f] + (double)benc[f];
    double h  = h0 * wf0 * wf1 * wf2;
    epid[wave][lane] = h;
    double pre = (double)bt1[lane];
    for (int m = 0; m < 64; ++m) pre += epid[wave][m] * (double)Wt1[m*64 + lane];
    double tv = tanh(pre);
    float gv = (float)((1.0 - tv * tv) * (double)Wt2[lane]);

    float p1 = (float)(h0 * wf1 * wf2);   // pairs with layer a
    float p2 = (float)(h0 * wf0 * wf2);   // layer b
    float p3 = (float)(h0 * wf0 * wf1);   // layer c

    // fused: dv = g @ Wt1^T
    epif[wave][lane] = gv;
    float dv = 0.f;
    for (int m = 0; m < 64; ++m) dv = fmaf(epif[wave][m], Wt1[lane*64 + m], dv);

    float* co = Cout + atom * 192;
    epif[wave][lane] = dv * p1;
    float c0 = 0.f;
    for (int m = 0; m < 64; ++m) c0 = fmaf(epif[wave][m], W2a[lane*64 + m], c0);
    co[lane] = c0;

    epif[wave][lane] = dv * p2;
    float c1 = 0.f;
    for (int m = 0; m < 64; ++m) c1 = fmaf(epif[wave][m], W2b[lane*64 + m], c1);
    co[64 + lane] = c1;

    epif[wave][lane] = dv * p3;
    float c2 = 0.f;
    for (int m = 0; m < 64; ++m) c2 = fmaf(epif[wave][m], W2c[lane*64 + m], c2);
    co[128 + lane] = c2;
}

// ------- backward: f-lane layout, unordered pairs, PT=8 pair register tile -------
__global__ __launch_bounds__(1024, 4) void k_bwd(
    const float* __restrict__ dws,
    const float* __restrict__ mus, const float* __restrict__ gamma,
    const float2* __restrict__ wu,
    const float* __restrict__ b1a, const float* __restrict__ b1b, const float* __restrict__ b1c,
    const float* __restrict__ C, float* __restrict__ T)
{
    __shared__ float2 wus[3 * KK * FF];    // 76800 B  [l][k][f]
    __shared__ float  rbfs[16][KK][PT];    // 25600 B
    __shared__ float  dsh[16][PT];
    __shared__ float  mus_s[64];

    int tid = threadIdx.x;
    for (int idx = tid; idx < 3 * KK * FF; idx += 1024) wus[idx] = wu[idx];
    if (tid < KK) mus_s[tid] = mus[tid];
    __syncthreads();

    int wave = tid >> 6, lane = tid & 63;
    int atom = blockIdx.x * 16 + wave;
    int b = atom >> 7, i = atom & 127;
    float gam = gamma[0];
    float n2g = -2.f * gam;
    const float* drow = dws + (atom << 7);
    const float* ci = C + atom * 192;
    float ci0 = ci[lane], ci1 = ci[64 + lane], ci2 = ci[128 + lane];
    float bb0 = b1a[lane], bb1 = b1b[lane], bb2 = b1c[lane];
    float* Tb = T + ((size_t)b << 14);

    for (int t = 0; t < 8; ++t) {
        if (lane < PT) {
            int off = 1 + t * PT + lane;
            dsh[wave][lane] = drow[(i + off) & 127];
        }
        #pragma unroll
        for (int pass = 0; pass < 7; ++pass) {
            int idx = lane + (pass << 6);
            if (idx < KK * PT) {
                int k = idx >> 3, p = idx & 7;
                float dd = dsh[wave][p] - mus_s[k];
                rbfs[wave][k][p] = __expf(-gam * dd * dd);
            }
        }
        float z0[PT], z1[PT], z2[PT], v0[PT], v1[PT], v2[PT];
        #pragma unroll
        for (int p = 0; p < PT; ++p) {
            z0[p] = 0.f; z1[p] = 0.f; z2[p] = 0.f;
            v0[p] = 0.f; v1[p] = 0.f; v2[p] = 0.f;
        }
        #pragma unroll 2
        for (int k = 0; k < KK; ++k) {
            float2 w0 = wus[(k << 6) + lane];
            float2 w1 = wus[KK * FF + (k << 6) + lane];
            float2 w2 = wus[2 * KK * FF + (k << 6) + lane];
            float rr[PT];
            {
                const float4* rp4 = (const float4*)(&rbfs[wave][k][0]);
                float4 a0 = rp4[0], a1 = rp4[1];
                *(float4*)&rr[0] = a0; *(float4*)&rr[4] = a1;
            }
            #pragma unroll
            for (int p = 0; p < PT; ++p) {
                z0[p] = fmaf(rr[p], w0.x, z0[p]);
                v0[p] = fmaf(rr[p], w0.y, v0[p]);
                z1[p] = fmaf(rr[p], w1.x, z1[p]);
                v1[p] = fmaf(rr[p], w1.y, v1[p]);
                z2[p] = fmaf(rr[p], w2.x, z2[p]);
                v2[p] = fmaf(rr[p], w2.y, v2[p]);
            }
        }
        float vmine = 0.f;
        #pragma unroll
        for (int p = 0; p < PT; ++p) {
            float d = dsh[wave][p];
            float n2gd = n2g * d;
            float zb0 = z0[p] + bb0, zb1 = z1[p] + bb1, zb2 = z2[p] + bb2;
            float s0 = __builtin_amdgcn_rcpf(1.f + __expf(-zb0));
            float s1 = __builtin_amdgcn_rcpf(1.f + __expf(-zb1));
            float s2 = __builtin_amdgcn_rcpf(1.f + __expf(-zb2));
            float y0 = fmaf(n2gd, z0[p], v0[p]);
            float y1 = fmaf(n2gd, z1[p], v1[p]);
            float y2 = fmaf(n2gd, z2[p], v2[p]);
            float g0 = s0 * y0, g1 = s1 * y1, g2 = s2 * y2;
            int a = (i + 1 + t * PT + p) & 127;
            const float* ca = C + (((b << 7) + a) * 192);
            float red = fmaf(ci0, g0, fmaf(ci1, g1, ci2 * g2));
            red = fmaf(ca[lane], g0, red);
            red = fmaf(ca[64 + lane], g1, red);
            red = fmaf(ca[128 + lane], g2, red);
            #pragma unroll
            for (int o = 1; o < 64; o <<= 1) red += __shfl_xor(red, o);
            if (lane == p) vmine = red;
        }
        if (lane < PT) {
            int off = 1 + t * PT + lane;
            if (off < 64 || i < 64) {
                int a = (i + off) & 127;
                Tb[(i << 7) + a] = vmine;
                Tb[(a << 7) + i] = vmine;
            }
        }
    }
}

__global__ __launch_bounds__(256) void k_force(
    const float* __restrict__ xs, const float* __restrict__ dws,
    const float* __restrict__ T, float* __restrict__ Fr)
{
    int tid = threadIdx.x;
    int wave = tid >> 6, lane = tid & 63;
    int atom = blockIdx.x * 4 + wave;
    int i = atom & 127;
    int b = atom >> 7;
    const float* xb = xs + b * (NN * 3);
    float xi0 = xb[i*3], xi1 = xb[i*3+1], xi2 = xb[i*3+2];
    const float* drow = dws + (atom << 7);
    const float* trow = T + (atom << 7);
    float fx = 0.f, fy = 0.f, fz = 0.f;
    for (int it = lane; it < 127; it += 64) {
        int aa = (i + 1 + it) & 127;
        float coef = trow[aa] / drow[aa];
        fx += coef * (xi0 - xb[aa*3]);
        fy += coef * (xi1 - xb[aa*3+1]);
        fz += coef * (xi2 - xb[aa*3+2]);
    }
    #pragma unroll
    for (int off = 1; off < 64; off <<= 1) {
        fx += __shfl_xor(fx, off);
        fy += __shfl_xor(fy, off);
        fz += __shfl_xor(fz, off);
    }
    if (lane == 0) {
        Fr[atom*3]   = fx;
        Fr[atom*3+1] = fy;
        Fr[atom*3+2] = fz;
    }
}

__global__ __launch_bounds__(128) void k_out(const float* __restrict__ Fr, float* __restrict__ out)
{
    __shared__ float rs[3][128];
    int b = blockIdx.x, n = threadIdx.x;
    float g0 = Fr[(b*128+n)*3], g1 = Fr[(b*128+n)*3+1], g2 = Fr[(b*128+n)*3+2];
    rs[0][n] = g0; rs[1][n] = g1; rs[2][n] = g2;
    __syncthreads();
    for (int s = 64; s > 0; s >>= 1) {
        if (n < s) {
            rs[0][n] += rs[0][n+s];
            rs[1][n] += rs[1][n+s];
            rs[2][n] += rs[2][n+s];
        }
        __syncthreads();
    }
    float m0 = rs[0][0] * (1.f/128.f);
    float m1 = rs[1][0] * (1.f/128.f);
    float m2 = rs[2][0] * (1.f/128.f);
    out[b*384 + n*3 + 0] = m0 - g0;
    out[b*384 + n*3 + 1] = m1 - g1;
    out[b*384 + n*3 + 2] = m2 - g2;
}

extern "C" void kernel_launch(void* const* d_in, const int* in_sizes, int n_in,
                              void* d_out, int out_size, void* d_ws, size_t ws_size,
                              hipStream_t stream)
{
    const float* xs   = (const float*)d_in[1];
    const float* mus  = (const float*)d_in[2];
    const float* gam  = (const float*)d_in[3];
    const float* Wenc = (const float*)d_in[4];
    const float* benc = (const float*)d_in[5];
    const float* W1a  = (const float*)d_in[6];
    const float* b1a  = (const float*)d_in[7];
    const float* W2a  = (const float*)d_in[8];
    const float* b2a  = (const float*)d_in[9];
    const float* W1b  = (const float*)d_in[10];
    const float* b1b  = (const float*)d_in[11];
    const float* W2b  = (const float*)d_in[12];
    const float* b2b  = (const float*)d_in[13];
    const float* W1c  = (const float*)d_in[14];
    const float* b1c  = (const float*)d_in[15];
    const float* W2c  = (const float*)d_in[16];
    const float* b2c  = (const float*)d_in[17];
    const float* Wt1  = (const float*)d_in[18];
    const float* bt1  = (const float*)d_in[19];
    const float* Wt2  = (const float*)d_in[20];

    float* ws  = (float*)d_ws;
    float* dws = ws;
    float* T   = ws + 524288;
    float2* wu = (float2*)(ws + 1048576);
    float* C   = ws + 2097152;
    float* Fr  = ws + 2883584;
    float* out = (float*)d_out;

    k_dist <<<2048, 256, 0, stream>>>(xs, dws);
    k_prep <<<38, 256, 0, stream>>>(W1a, W1b, W1c, mus, gam, wu);
    k_fwd  <<<512, 512, 0, stream>>>(dws, mus, gam, W1a, W1b, W1c, b1a, b1b, b1c,
                                     W2a, W2b, W2c, b2a, b2b, b2c, Wenc, benc,
                                     Wt1, bt1, Wt2, C);
    k_bwd  <<<256, 1024, 0, stream>>>(dws, mus, gam, wu, b1a, b1b, b1c, C, T);
    k_force<<<1024, 256, 0, stream>>>(xs, dws, T, Fr);
    k_out  <<<32, 128, 0, stream>>>(Fr, out);
}

// Round 12
// 342.157 us; speedup vs baseline: 1.2302x; 1.2302x over previous
//
#include <hip/hip_runtime.h>
#include <math.h>

#define NN 128
#define FF 64
#define KK 50
#define PT 8
#define EPSV 1e-6f

// ws layout (floats):
// dws: [B*N*N]      off 0         (524288)
// T:   [B*N*N]      off 524288
// wu:  [3*50*64*2]  off 1048576
// C:   [B*N*3*64]   off 2097152
// Fr:  [B*N*3]      off 2883584

__device__ __forceinline__ float softplus_fast(float z) {
    float e = __expf(-fabsf(z));
    float l = __logf(1.f + e);
    return fmaxf(z, 0.f) + l;
}

__global__ __launch_bounds__(256) void k_dist(const float* __restrict__ xs, float* __restrict__ dws)
{
    int tid = blockIdx.x * 256 + threadIdx.x;
    int b = tid >> 14;
    int rem = tid & 16383;
    int i = rem >> 7, a = rem & 127;
    const float* xb = xs + b * (NN * 3);
    float dx = xb[i*3+0] - xb[a*3+0];
    float dy = xb[i*3+1] - xb[a*3+1];
    float dz = xb[i*3+2] - xb[a*3+2];
    dws[tid] = sqrtf(dx*dx + dy*dy + dz*dz + EPSV);
}

// build (w, u) pairs for bwd: u[l][k][f] = 2*gamma*mu_k * W1l[k][f]
__global__ __launch_bounds__(256) void k_prep(
    const float* __restrict__ W1a, const float* __restrict__ W1b, const float* __restrict__ W1c,
    const float* __restrict__ mus, const float* __restrict__ gamma,
    float2* __restrict__ wu)
{
    int idx = blockIdx.x * 256 + threadIdx.x;   // 3*50*64 = 9600
    if (idx < 3 * KK * FF) {
        int l = idx / (KK * FF), r = idx - l * (KK * FF);
        int k = r >> 6;
        const float* W = (l == 0) ? W1a : (l == 1) ? W1b : W1c;
        float w = W[r];
        wu[idx] = make_float2(w, 2.f * gamma[0] * mus[k] * w);
    }
}

// ------- forward: 1024-thr / 16-wave blocks (k_bwd's proven shape), R8 inner loop -------
__global__ __launch_bounds__(1024, 4) void k_fwd(
    const float* __restrict__ dws,
    const float* __restrict__ mus, const float* __restrict__ gamma,
    const float* __restrict__ W1a, const float* __restrict__ W1b, const float* __restrict__ W1c,
    const float* __restrict__ b1a, const float* __restrict__ b1b, const float* __restrict__ b1c,
    const float* __restrict__ W2a, const float* __restrict__ W2b, const float* __restrict__ W2c,
    const float* __restrict__ b2a, const float* __restrict__ b2b, const float* __restrict__ b2c,
    const float* __restrict__ Wenc, const float* __restrict__ benc,
    const float* __restrict__ Wt1, const float* __restrict__ bt1, const float* __restrict__ Wt2,
    float* __restrict__ Cout)
{
    __shared__ float2 wab[KK * FF];        // (wa,wb)  25600 B
    __shared__ float  wcs[KK * FF];        // wc       12800 B
    __shared__ float  rbfs[16][KK][16];    // 51200 B
    __shared__ float  dsh[16][16];         // 1024 B
    __shared__ float  mus_s[64];
    __shared__ double epid[16][FF];        // 8192 B
    __shared__ float  epif[16][FF];        // 4096 B

    int tid = threadIdx.x;
    for (int idx = tid; idx < KK * FF; idx += 1024) {
        wab[idx] = make_float2(W1a[idx], W1b[idx]);
        wcs[idx] = W1c[idx];
    }
    if (tid < KK) mus_s[tid] = mus[tid];
    __syncthreads();

    int wave = tid >> 6, lane = tid & 63, f = lane;
    int atom = blockIdx.x * 16 + wave;
    int i = atom & 127;
    float gam = gamma[0];
    float bb0 = b1a[f], bb1 = b1b[f], bb2 = b1c[f];
    double us0 = 0.0, us1 = 0.0, us2 = 0.0;
    const float* drow = dws + (atom << 7);

    #pragma unroll 1
    for (int t = 0; t < 8; ++t) {
        if (lane < 16) {
            int aa = (i + 1 + 16 * t + lane) & 127;
            dsh[wave][lane] = drow[aa];
        }
        #pragma unroll
        for (int pass = 0; pass < 13; ++pass) {
            int idx = lane + (pass << 6);
            int k = idx >> 4, p = idx & 15;
            if (k < KK) {
                float dd = dsh[wave][p] - mus_s[k];
                rbfs[wave][k][p] = __expf(-gam * dd * dd);
            }
        }
        float z0[16], z1[16], z2[16];
        #pragma unroll
        for (int p = 0; p < 16; ++p) { z0[p] = bb0; z1[p] = bb1; z2[p] = bb2; }
        #pragma unroll 2
        for (int k = 0; k < KK; ++k) {
            float2 wv = wab[(k << 6) + f];
            float  wc = wcs[(k << 6) + f];
            float rr[16];
            {
                const float4* rp4 = (const float4*)(&rbfs[wave][k][0]);
                float4 a0 = rp4[0], a1 = rp4[1], a2 = rp4[2], a3 = rp4[3];
                *(float4*)&rr[0]  = a0; *(float4*)&rr[4]  = a1;
                *(float4*)&rr[8]  = a2; *(float4*)&rr[12] = a3;
            }
            #pragma unroll
            for (int p = 0; p < 16; ++p) {
                z0[p] = fmaf(rr[p], wv.x, z0[p]);
                z1[p] = fmaf(rr[p], wv.y, z1[p]);
                z2[p] = fmaf(rr[p], wc,   z2[p]);
            }
        }
        int base = 16 * t;
        #pragma unroll
        for (int p = 0; p < 16; ++p) {
            if (base + p < 127) {
                us0 += (double)softplus_fast(z0[p]);
                us1 += (double)softplus_fast(z1[p]);
                us2 += (double)softplus_fast(z2[p]);
            }
        }
    }

    // per-atom epilogue (wave-local, double precision for h/pre path)
    double wf0, wf1, wf2;
    {
        epid[wave][lane] = us0;
        double acc = 0.0;
        for (int m = 0; m < 64; ++m) acc += epid[wave][m] * (double)W2a[m*64 + f];
        wf0 = 1.0 + acc + 127.0 * (double)b2a[f];

        epid[wave][lane] = us1;
        double acc1 = 0.0;
        for (int m = 0; m < 64; ++m) acc1 += epid[wave][m] * (double)W2b[m*64 + f];
        wf1 = 1.0 + acc1 + 127.0 * (double)b2b[f];

        epid[wave][lane] = us2;
        double acc2 = 0.0;
        for (int m = 0; m < 64; ++m) acc2 += epid[wave][m] * (double)W2c[m*64 + f];
        wf2 = 1.0 + acc2 + 127.0 * (double)b2c[f];
    }
    double h0 = (double)Wenc[f] + (double)benc[f];
    double h  = h0 * wf0 * wf1 * wf2;
    epid[wave][lane] = h;
    double pre = (double)bt1[lane];
    for (int m = 0; m < 64; ++m) pre += epid[wave][m] * (double)Wt1[m*64 + lane];
    double tv = tanh(pre);
    float gv = (float)((1.0 - tv * tv) * (double)Wt2[lane]);

    float p1 = (float)(h0 * wf1 * wf2);   // pairs with layer a
    float p2 = (float)(h0 * wf0 * wf2);   // layer b
    float p3 = (float)(h0 * wf0 * wf1);   // layer c

    // fused: dv = g @ Wt1^T
    epif[wave][lane] = gv;
    float dv = 0.f;
    for (int m = 0; m < 64; ++m) dv = fmaf(epif[wave][m], Wt1[lane*64 + m], dv);

    float* co = Cout + atom * 192;
    epif[wave][lane] = dv * p1;
    float c0 = 0.f;
    for (int m = 0; m < 64; ++m) c0 = fmaf(epif[wave][m], W2a[lane*64 + m], c0);
    co[lane] = c0;

    epif[wave][lane] = dv * p2;
    float c1 = 0.f;
    for (int m = 0; m < 64; ++m) c1 = fmaf(epif[wave][m], W2b[lane*64 + m], c1);
    co[64 + lane] = c1;

    epif[wave][lane] = dv * p3;
    float c2 = 0.f;
    for (int m = 0; m < 64; ++m) c2 = fmaf(epif[wave][m], W2c[lane*64 + m], c2);
    co[128 + lane] = c2;
}

// ------- backward: f-lane layout, unordered pairs, PT=8 pair register tile -------
__global__ __launch_bounds__(1024, 4) void k_bwd(
    const float* __restrict__ dws,
    const float* __restrict__ mus, const float* __restrict__ gamma,
    const float2* __restrict__ wu,
    const float* __restrict__ b1a, const float* __restrict__ b1b, const float* __restrict__ b1c,
    const float* __restrict__ C, float* __restrict__ T)
{
    __shared__ float2 wus[3 * KK * FF];    // 76800 B  [l][k][f]
    __shared__ float  rbfs[16][KK][PT];    // 25600 B
    __shared__ float  dsh[16][PT];
    __shared__ float  mus_s[64];

    int tid = threadIdx.x;
    for (int idx = tid; idx < 3 * KK * FF; idx += 1024) wus[idx] = wu[idx];
    if (tid < KK) mus_s[tid] = mus[tid];
    __syncthreads();

    int wave = tid >> 6, lane = tid & 63;
    int atom = blockIdx.x * 16 + wave;
    int b = atom >> 7, i = atom & 127;
    float gam = gamma[0];
    float n2g = -2.f * gam;
    const float* drow = dws + (atom << 7);
    const float* ci = C + atom * 192;
    float ci0 = ci[lane], ci1 = ci[64 + lane], ci2 = ci[128 + lane];
    float bb0 = b1a[lane], bb1 = b1b[lane], bb2 = b1c[lane];
    float* Tb = T + ((size_t)b << 14);

    for (int t = 0; t < 8; ++t) {
        if (lane < PT) {
            int off = 1 + t * PT + lane;
            dsh[wave][lane] = drow[(i + off) & 127];
        }
        #pragma unroll
        for (int pass = 0; pass < 7; ++pass) {
            int idx = lane + (pass << 6);
            if (idx < KK * PT) {
                int k = idx >> 3, p = idx & 7;
                float dd = dsh[wave][p] - mus_s[k];
                rbfs[wave][k][p] = __expf(-gam * dd * dd);
            }
        }
        float z0[PT], z1[PT], z2[PT], v0[PT], v1[PT], v2[PT];
        #pragma unroll
        for (int p = 0; p < PT; ++p) {
            z0[p] = 0.f; z1[p] = 0.f; z2[p] = 0.f;
            v0[p] = 0.f; v1[p] = 0.f; v2[p] = 0.f;
        }
        #pragma unroll 2
        for (int k = 0; k < KK; ++k) {
            float2 w0 = wus[(k << 6) + lane];
            float2 w1 = wus[KK * FF + (k << 6) + lane];
            float2 w2 = wus[2 * KK * FF + (k << 6) + lane];
            float rr[PT];
            {
                const float4* rp4 = (const float4*)(&rbfs[wave][k][0]);
                float4 a0 = rp4[0], a1 = rp4[1];
                *(float4*)&rr[0] = a0; *(float4*)&rr[4] = a1;
            }
            #pragma unroll
            for (int p = 0; p < PT; ++p) {
                z0[p] = fmaf(rr[p], w0.x, z0[p]);
                v0[p] = fmaf(rr[p], w0.y, v0[p]);
                z1[p] = fmaf(rr[p], w1.x, z1[p]);
                v1[p] = fmaf(rr[p], w1.y, v1[p]);
                z2[p] = fmaf(rr[p], w2.x, z2[p]);
                v2[p] = fmaf(rr[p], w2.y, v2[p]);
            }
        }
        float vmine = 0.f;
        #pragma unroll
        for (int p = 0; p < PT; ++p) {
            float d = dsh[wave][p];
            float n2gd = n2g * d;
            float zb0 = z0[p] + bb0, zb1 = z1[p] + bb1, zb2 = z2[p] + bb2;
            float s0 = __builtin_amdgcn_rcpf(1.f + __expf(-zb0));
            float s1 = __builtin_amdgcn_rcpf(1.f + __expf(-zb1));
            float s2 = __builtin_amdgcn_rcpf(1.f + __expf(-zb2));
            float y0 = fmaf(n2gd, z0[p], v0[p]);
            float y1 = fmaf(n2gd, z1[p], v1[p]);
            float y2 = fmaf(n2gd, z2[p], v2[p]);
            float g0 = s0 * y0, g1 = s1 * y1, g2 = s2 * y2;
            int a = (i + 1 + t * PT + p) & 127;
            const float* ca = C + (((b << 7) + a) * 192);
            float red = fmaf(ci0, g0, fmaf(ci1, g1, ci2 * g2));
            red = fmaf(ca[lane], g0, red);
            red = fmaf(ca[64 + lane], g1, red);
            red = fmaf(ca[128 + lane], g2, red);
            #pragma unroll
            for (int o = 1; o < 64; o <<= 1) red += __shfl_xor(red, o);
            if (lane == p) vmine = red;
        }
        if (lane < PT) {
            int off = 1 + t * PT + lane;
            if (off < 64 || i < 64) {
                int a = (i + off) & 127;
                Tb[(i << 7) + a] = vmine;
                Tb[(a << 7) + i] = vmine;
            }
        }
    }
}

__global__ __launch_bounds__(256) void k_force(
    const float* __restrict__ xs, const float* __restrict__ dws,
    const float* __restrict__ T, float* __restrict__ Fr)
{
    int tid = threadIdx.x;
    int wave = tid >> 6, lane = tid & 63;
    int atom = blockIdx.x * 4 + wave;
    int i = atom & 127;
    int b = atom >> 7;
    const float* xb = xs + b * (NN * 3);
    float xi0 = xb[i*3], xi1 = xb[i*3+1], xi2 = xb[i*3+2];
    const float* drow = dws + (atom << 7);
    const float* trow = T + (atom << 7);
    float fx = 0.f, fy = 0.f, fz = 0.f;
    for (int it = lane; it < 127; it += 64) {
        int aa = (i + 1 + it) & 127;
        float coef = trow[aa] / drow[aa];
        fx += coef * (xi0 - xb[aa*3]);
        fy += coef * (xi1 - xb[aa*3+1]);
        fz += coef * (xi2 - xb[aa*3+2]);
    }
    #pragma unroll
    for (int off = 1; off < 64; off <<= 1) {
        fx += __shfl_xor(fx, off);
        fy += __shfl_xor(fy, off);
        fz += __shfl_xor(fz, off);
    }
    if (lane == 0) {
        Fr[atom*3]   = fx;
        Fr[atom*3+1] = fy;
        Fr[atom*3+2] = fz;
    }
}

__global__ __launch_bounds__(128) void k_out(const float* __restrict__ Fr, float* __restrict__ out)
{
    __shared__ float rs[3][128];
    int b = blockIdx.x, n = threadIdx.x;
    float g0 = Fr[(b*128+n)*3], g1 = Fr[(b*128+n)*3+1], g2 = Fr[(b*128+n)*3+2];
    rs[0][n] = g0; rs[1][n] = g1; rs[2][n] = g2;
    __syncthreads();
    for (int s = 64; s > 0; s >>= 1) {
        if (n < s) {
            rs[0][n] += rs[0][n+s];
            rs[1][n] += rs[1][n+s];
            rs[2][n] += rs[2][n+s];
        }
        __syncthreads();
    }
    float m0 = rs[0][0] * (1.f/128.f);
    float m1 = rs[1][0] * (1.f/128.f);
    float m2 = rs[2][0] * (1.f/128.f);
    out[b*384 + n*3 + 0] = m0 - g0;
    out[b*384 + n*3 + 1] = m1 - g1;
    out[b*384 + n*3 + 2] = m2 - g2;
}

extern "C" void kernel_launch(void* const* d_in, const int* in_sizes, int n_in,
                              void* d_out, int out_size, void* d_ws, size_t ws_size,
                              hipStream_t stream)
{
    const float* xs   = (const float*)d_in[1];
    const float* mus  = (const float*)d_in[2];
    const float* gam  = (const float*)d_in[3];
    const float* Wenc = (const float*)d_in[4];
    const float* benc = (const float*)d_in[5];
    const float* W1a  = (const float*)d_in[6];
    const float* b1a  = (const float*)d_in[7];
    const float* W2a  = (const float*)d_in[8];
    const float* b2a  = (const float*)d_in[9];
    const float* W1b  = (const float*)d_in[10];
    const float* b1b  = (const float*)d_in[11];
    const float* W2b  = (const float*)d_in[12];
    const float* b2b  = (const float*)d_in[13];
    const float* W1c  = (const float*)d_in[14];
    const float* b1c  = (const float*)d_in[15];
    const float* W2c  = (const float*)d_in[16];
    const float* b2c  = (const float*)d_in[17];
    const float* Wt1  = (const float*)d_in[18];
    const float* bt1  = (const float*)d_in[19];
    const float* Wt2  = (const float*)d_in[20];

    float* ws  = (float*)d_ws;
    float* dws = ws;
    float* T   = ws + 524288;
    float2* wu = (float2*)(ws + 1048576);
    float* C   = ws + 2097152;
    float* Fr  = ws + 2883584;
    float* out = (float*)d_out;

    k_dist <<<2048, 256, 0, stream>>>(xs, dws);
    k_prep <<<38, 256, 0, stream>>>(W1a, W1b, W1c, mus, gam, wu);
    k_fwd  <<<256, 1024, 0, stream>>>(dws, mus, gam, W1a, W1b, W1c, b1a, b1b, b1c,
                                      W2a, W2b, W2c, b2a, b2b, b2c, Wenc, benc,
                                      Wt1, bt1, Wt2, C);
    k_bwd  <<<256, 1024, 0, stream>>>(dws, mus, gam, wu, b1a, b1b, b1c, C, T);
    k_force<<<1024, 256, 0, stream>>>(xs, dws, T, Fr);
    k_out  <<<32, 128, 0, stream>>>(Fr, out);
}

// Round 13
// 290.159 us; speedup vs baseline: 1.4507x; 1.1792x over previous
//
#include <hip/hip_runtime.h>
#include <math.h>

#define NN 128
#define FF 64
#define KK 50
#define PT 8
#define NTAB 1024
#define EPSV 1e-6f

// ws layout (floats):
// dws: [B*N*N]        off 0
// T:   [B*N*N]        off 524288
// wu:  [3*50*64*2]    off 1048576  (19200 floats)
// A:   [(NTAB+1)*192] float2       off 1067776  (393600 floats -> ends 1461376)
// C:   [B*N*3*64]     off 2097152
// Fr:  [B*N*3]        off 2883584

__global__ __launch_bounds__(256) void k_dist(const float* __restrict__ xs, float* __restrict__ dws)
{
    int tid = blockIdx.x * 256 + threadIdx.x;
    int b = tid >> 14;
    int rem = tid & 16383;
    int i = rem >> 7, a = rem & 127;
    const float* xb = xs + b * (NN * 3);
    float dx = xb[i*3+0] - xb[a*3+0];
    float dy = xb[i*3+1] - xb[a*3+1];
    float dz = xb[i*3+2] - xb[a*3+2];
    dws[tid] = sqrtf(dx*dx + dy*dy + dz*dz + EPSV);
}

// build (w, u) pairs for bwd: u[l][k][f] = 2*gamma*mu_k * W1l[k][f]
__global__ __launch_bounds__(256) void k_prep(
    const float* __restrict__ W1a, const float* __restrict__ W1b, const float* __restrict__ W1c,
    const float* __restrict__ mus, const float* __restrict__ gamma,
    float2* __restrict__ wu)
{
    int idx = blockIdx.x * 256 + threadIdx.x;   // 3*50*64 = 9600
    if (idx < 3 * KK * FF) {
        int l = idx / (KK * FF), r = idx - l * (KK * FF);
        int k = r >> 6;
        const float* W = (l == 0) ? W1a : (l == 1) ? W1b : W1c;
        float w = W[r];
        wu[idx] = make_float2(w, 2.f * gamma[0] * mus[k] * w);
    }
}

// build radial table: A[node*192 + l*64 + f] = (G, h*G')
// G(d) = softplus(z_l[f](d)), G' = sigmoid(z)*dz/dd  (double-precision build)
__global__ __launch_bounds__(256) void k_tab(
    const float* __restrict__ W1a, const float* __restrict__ W1b, const float* __restrict__ W1c,
    const float* __restrict__ b1a, const float* __restrict__ b1b, const float* __restrict__ b1c,
    const float* __restrict__ mus, const float* __restrict__ gamma,
    float2* __restrict__ A)
{
    int idx = blockIdx.x * 256 + threadIdx.x;
    if (idx >= (NTAB + 1) * 192) return;
    int node = idx / 192, r = idx - node * 192;
    int l = r >> 6, f = r & 63;
    const float* W  = (l == 0) ? W1a : (l == 1) ? W1b : W1c;
    const float* bb = (l == 0) ? b1a : (l == 1) ? b1b : b1c;
    double h = 10.0 / (double)NTAB;
    double d = (double)node * h;
    float gam = gamma[0];
    double z = (double)bb[f], y = 0.0;
    for (int k = 0; k < KK; ++k) {
        double x = d - (double)mus[k];
        float xf = (float)x;
        double e = (double)__expf(-gam * xf * xf);
        double w = (double)W[k * 64 + f];
        z += w * e;
        y += w * (-2.0 * (double)gam * x) * e;
    }
    double G  = (z > 0.0) ? z + log1p(exp(-z)) : log1p(exp(z));
    double sg = 1.0 / (1.0 + exp(-z));
    A[idx] = make_float2((float)G, (float)(sg * y * h));
}

// ------- forward via table: per pair 6 float2 loads + Hermite; fused epilogue -------
__global__ __launch_bounds__(512) void k_fwd(
    const float* __restrict__ dws, const float2* __restrict__ A,
    const float* __restrict__ W2a, const float* __restrict__ W2b, const float* __restrict__ W2c,
    const float* __restrict__ b2a, const float* __restrict__ b2b, const float* __restrict__ b2c,
    const float* __restrict__ Wenc, const float* __restrict__ benc,
    const float* __restrict__ Wt1, const float* __restrict__ bt1, const float* __restrict__ Wt2,
    float* __restrict__ Cout)
{
    __shared__ double epid[8][FF];
    __shared__ float  epif[8][FF];

    int tid = threadIdx.x;
    int wave = tid >> 6, lane = tid & 63, f = lane;
    int atom = blockIdx.x * 8 + wave;
    int i = atom & 127;
    const float* drow = dws + (atom << 7);
    const float invh = (float)NTAB / 10.0f;
    double us0 = 0.0, us1 = 0.0, us2 = 0.0;

    #pragma unroll 1
    for (int t = 0; t < 8; ++t) {
        float ut0 = 0.f, ut1 = 0.f, ut2 = 0.f;
        #pragma unroll 4
        for (int p = 0; p < 16; ++p) {
            int pi = 16 * t + p;
            bool valid = pi < 127;
            float d = drow[(i + 1 + pi) & 127];
            float fd = fminf(d * invh, (float)NTAB - 0.001f);
            float jf = floorf(fd);
            float tt = fd - jf;
            int j = (int)jf;
            const float2* r0 = A + j * 192 + f;
            float2 a0 = r0[0],   b0 = r0[192];
            float2 a1 = r0[64],  b1 = r0[256];
            float2 a2 = r0[128], b2 = r0[320];
            float t2 = tt * tt, t3 = t2 * tt;
            float h00 = 2.f * t3 - 3.f * t2 + 1.f;
            float h01 = 1.f - h00;
            float h10 = t3 - 2.f * t2 + tt;
            float h11 = t3 - t2;
            float g0 = h00 * a0.x + h10 * a0.y + h01 * b0.x + h11 * b0.y;
            float g1 = h00 * a1.x + h10 * a1.y + h01 * b1.x + h11 * b1.y;
            float g2 = h00 * a2.x + h10 * a2.y + h01 * b2.x + h11 * b2.y;
            ut0 += valid ? g0 : 0.f;
            ut1 += valid ? g1 : 0.f;
            ut2 += valid ? g2 : 0.f;
        }
        us0 += (double)ut0; us1 += (double)ut1; us2 += (double)ut2;
    }

    // per-atom epilogue (wave-local, double precision for h/pre path)
    double wf0, wf1, wf2;
    {
        epid[wave][lane] = us0;
        double acc = 0.0;
        for (int m = 0; m < 64; ++m) acc += epid[wave][m] * (double)W2a[m*64 + f];
        wf0 = 1.0 + acc + 127.0 * (double)b2a[f];

        epid[wave][lane] = us1;
        double acc1 = 0.0;
        for (int m = 0; m < 64; ++m) acc1 += epid[wave][m] * (double)W2b[m*64 + f];
        wf1 = 1.0 + acc1 + 127.0 * (double)b2b[f];

        epid[wave][lane] = us2;
        double acc2 = 0.0;
        for (int m = 0; m < 64; ++m) acc2 += epid[wave][m] * (double)W2c[m*64 + f];
        wf2 = 1.0 + acc2 + 127.0 * (double)b2c[f];
    }
    double h0 = (double)Wenc[f] + (double)benc[f];
    double h  = h0 * wf0 * wf1 * wf2;
    epid[wave][lane] = h;
    double pre = (double)bt1[lane];
    for (int m = 0; m < 64; ++m) pre += epid[wave][m] * (double)Wt1[m*64 + lane];
    double tv = tanh(pre);
    float gv = (float)((1.0 - tv * tv) * (double)Wt2[lane]);

    float p1 = (float)(h0 * wf1 * wf2);   // pairs with layer a
    float p2 = (float)(h0 * wf0 * wf2);   // layer b
    float p3 = (float)(h0 * wf0 * wf1);   // layer c

    // fused: dv = g @ Wt1^T
    epif[wave][lane] = gv;
    float dv = 0.f;
    for (int m = 0; m < 64; ++m) dv = fmaf(epif[wave][m], Wt1[lane*64 + m], dv);

    float* co = Cout + atom * 192;
    epif[wave][lane] = dv * p1;
    float c0 = 0.f;
    for (int m = 0; m < 64; ++m) c0 = fmaf(epif[wave][m], W2a[lane*64 + m], c0);
    co[lane] = c0;

    epif[wave][lane] = dv * p2;
    float c1 = 0.f;
    for (int m = 0; m < 64; ++m) c1 = fmaf(epif[wave][m], W2b[lane*64 + m], c1);
    co[64 + lane] = c1;

    epif[wave][lane] = dv * p3;
    float c2 = 0.f;
    for (int m = 0; m < 64; ++m) c2 = fmaf(epif[wave][m], W2c[lane*64 + m], c2);
    co[128 + lane] = c2;
}

// ------- backward: f-lane layout, unordered pairs, PT=8 pair register tile -------
__global__ __launch_bounds__(1024, 4) void k_bwd(
    const float* __restrict__ dws,
    const float* __restrict__ mus, const float* __restrict__ gamma,
    const float2* __restrict__ wu,
    const float* __restrict__ b1a, const float* __restrict__ b1b, const float* __restrict__ b1c,
    const float* __restrict__ C, float* __restrict__ T)
{
    __shared__ float2 wus[3 * KK * FF];    // 76800 B  [l][k][f]
    __shared__ float  rbfs[16][KK][PT];    // 25600 B
    __shared__ float  dsh[16][PT];
    __shared__ float  mus_s[64];

    int tid = threadIdx.x;
    for (int idx = tid; idx < 3 * KK * FF; idx += 1024) wus[idx] = wu[idx];
    if (tid < KK) mus_s[tid] = mus[tid];
    __syncthreads();

    int wave = tid >> 6, lane = tid & 63;
    int atom = blockIdx.x * 16 + wave;
    int b = atom >> 7, i = atom & 127;
    float gam = gamma[0];
    float n2g = -2.f * gam;
    const float* drow = dws + (atom << 7);
    const float* ci = C + atom * 192;
    float ci0 = ci[lane], ci1 = ci[64 + lane], ci2 = ci[128 + lane];
    float bb0 = b1a[lane], bb1 = b1b[lane], bb2 = b1c[lane];
    float* Tb = T + ((size_t)b << 14);

    for (int t = 0; t < 8; ++t) {
        if (lane < PT) {
            int off = 1 + t * PT + lane;
            dsh[wave][lane] = drow[(i + off) & 127];
        }
        #pragma unroll
        for (int pass = 0; pass < 7; ++pass) {
            int idx = lane + (pass << 6);
            if (idx < KK * PT) {
                int k = idx >> 3, p = idx & 7;
                float dd = dsh[wave][p] - mus_s[k];
                rbfs[wave][k][p] = __expf(-gam * dd * dd);
            }
        }
        float z0[PT], z1[PT], z2[PT], v0[PT], v1[PT], v2[PT];
        #pragma unroll
        for (int p = 0; p < PT; ++p) {
            z0[p] = 0.f; z1[p] = 0.f; z2[p] = 0.f;
            v0[p] = 0.f; v1[p] = 0.f; v2[p] = 0.f;
        }
        #pragma unroll 2
        for (int k = 0; k < KK; ++k) {
            float2 w0 = wus[(k << 6) + lane];
            float2 w1 = wus[KK * FF + (k << 6) + lane];
            float2 w2 = wus[2 * KK * FF + (k << 6) + lane];
            float rr[PT];
            {
                const float4* rp4 = (const float4*)(&rbfs[wave][k][0]);
                float4 a0 = rp4[0], a1 = rp4[1];
                *(float4*)&rr[0] = a0; *(float4*)&rr[4] = a1;
            }
            #pragma unroll
            for (int p = 0; p < PT; ++p) {
                z0[p] = fmaf(rr[p], w0.x, z0[p]);
                v0[p] = fmaf(rr[p], w0.y, v0[p]);
                z1[p] = fmaf(rr[p], w1.x, z1[p]);
                v1[p] = fmaf(rr[p], w1.y, v1[p]);
                z2[p] = fmaf(rr[p], w2.x, z2[p]);
                v2[p] = fmaf(rr[p], w2.y, v2[p]);
            }
        }
        float vmine = 0.f;
        #pragma unroll
        for (int p = 0; p < PT; ++p) {
            float d = dsh[wave][p];
            float n2gd = n2g * d;
            float zb0 = z0[p] + bb0, zb1 = z1[p] + bb1, zb2 = z2[p] + bb2;
            float s0 = __builtin_amdgcn_rcpf(1.f + __expf(-zb0));
            float s1 = __builtin_amdgcn_rcpf(1.f + __expf(-zb1));
            float s2 = __builtin_amdgcn_rcpf(1.f + __expf(-zb2));
            float y0 = fmaf(n2gd, z0[p], v0[p]);
            float y1 = fmaf(n2gd, z1[p], v1[p]);
            float y2 = fmaf(n2gd, z2[p], v2[p]);
            float g0 = s0 * y0, g1 = s1 * y1, g2 = s2 * y2;
            int a = (i + 1 + t * PT + p) & 127;
            const float* ca = C + (((b << 7) + a) * 192);
            float red = fmaf(ci0, g0, fmaf(ci1, g1, ci2 * g2));
            red = fmaf(ca[lane], g0, red);
            red = fmaf(ca[64 + lane], g1, red);
            red = fmaf(ca[128 + lane], g2, red);
            #pragma unroll
            for (int o = 1; o < 64; o <<= 1) red += __shfl_xor(red, o);
            if (lane == p) vmine = red;
        }
        if (lane < PT) {
            int off = 1 + t * PT + lane;
            if (off < 64 || i < 64) {
                int a = (i + off) & 127;
                Tb[(i << 7) + a] = vmine;
                Tb[(a << 7) + i] = vmine;
            }
        }
    }
}

__global__ __launch_bounds__(256) void k_force(
    const float* __restrict__ xs, const float* __restrict__ dws,
    const float* __restrict__ T, float* __restrict__ Fr)
{
    int tid = threadIdx.x;
    int wave = tid >> 6, lane = tid & 63;
    int atom = blockIdx.x * 4 + wave;
    int i = atom & 127;
    int b = atom >> 7;
    const float* xb = xs + b * (NN * 3);
    float xi0 = xb[i*3], xi1 = xb[i*3+1], xi2 = xb[i*3+2];
    const float* drow = dws + (atom << 7);
    const float* trow = T + (atom << 7);
    float fx = 0.f, fy = 0.f, fz = 0.f;
    for (int it = lane; it < 127; it += 64) {
        int aa = (i + 1 + it) & 127;
        float coef = trow[aa] / drow[aa];
        fx += coef * (xi0 - xb[aa*3]);
        fy += coef * (xi1 - xb[aa*3+1]);
        fz += coef * (xi2 - xb[aa*3+2]);
    }
    #pragma unroll
    for (int off = 1; off < 64; off <<= 1) {
        fx += __shfl_xor(fx, off);
        fy += __shfl_xor(fy, off);
        fz += __shfl_xor(fz, off);
    }
    if (lane == 0) {
        Fr[atom*3]   = fx;
        Fr[atom*3+1] = fy;
        Fr[atom*3+2] = fz;
    }
}

__global__ __launch_bounds__(128) void k_out(const float* __restrict__ Fr, float* __restrict__ out)
{
    __shared__ float rs[3][128];
    int b = blockIdx.x, n = threadIdx.x;
    float g0 = Fr[(b*128+n)*3], g1 = Fr[(b*128+n)*3+1], g2 = Fr[(b*128+n)*3+2];
    rs[0][n] = g0; rs[1][n] = g1; rs[2][n] = g2;
    __syncthreads();
    for (int s = 64; s > 0; s >>= 1) {
        if (n < s) {
            rs[0][n] += rs[0][n+s];
            rs[1][n] += rs[1][n+s];
            rs[2][n] += rs[2][n+s];
        }
        __syncthreads();
    }
    float m0 = rs[0][0] * (1.f/128.f);
    float m1 = rs[1][0] * (1.f/128.f);
    float m2 = rs[2][0] * (1.f/128.f);
    out[b*384 + n*3 + 0] = m0 - g0;
    out[b*384 + n*3 + 1] = m1 - g1;
    out[b*384 + n*3 + 2] = m2 - g2;
}

extern "C" void kernel_launch(void* const* d_in, const int* in_sizes, int n_in,
                              void* d_out, int out_size, void* d_ws, size_t ws_size,
                              hipStream_t stream)
{
    const float* xs   = (const float*)d_in[1];
    const float* mus  = (const float*)d_in[2];
    const float* gam  = (const float*)d_in[3];
    const float* Wenc = (const float*)d_in[4];
    const float* benc = (const float*)d_in[5];
    const float* W1a  = (const float*)d_in[6];
    const float* b1a  = (const float*)d_in[7];
    const float* W2a  = (const float*)d_in[8];
    const float* b2a  = (const float*)d_in[9];
    const float* W1b  = (const float*)d_in[10];
    const float* b1b  = (const float*)d_in[11];
    const float* W2b  = (const float*)d_in[12];
    const float* b2b  = (const float*)d_in[13];
    const float* W1c  = (const float*)d_in[14];
    const float* b1c  = (const float*)d_in[15];
    const float* W2c  = (const float*)d_in[16];
    const float* b2c  = (const float*)d_in[17];
    const float* Wt1  = (const float*)d_in[18];
    const float* bt1  = (const float*)d_in[19];
    const float* Wt2  = (const float*)d_in[20];

    float* ws  = (float*)d_ws;
    float* dws = ws;
    float* T   = ws + 524288;
    float2* wu = (float2*)(ws + 1048576);
    float2* A  = (float2*)(ws + 1067776);
    float* C   = ws + 2097152;
    float* Fr  = ws + 2883584;
    float* out = (float*)d_out;

    k_dist <<<2048, 256, 0, stream>>>(xs, dws);
    k_prep <<<38, 256, 0, stream>>>(W1a, W1b, W1c, mus, gam, wu);
    k_tab  <<<769, 256, 0, stream>>>(W1a, W1b, W1c, b1a, b1b, b1c, mus, gam, A);
    k_fwd  <<<512, 512, 0, stream>>>(dws, A, W2a, W2b, W2c, b2a, b2b, b2c,
                                     Wenc, benc, Wt1, bt1, Wt2, C);
    k_bwd  <<<256, 1024, 0, stream>>>(dws, mus, gam, wu, b1a, b1b, b1c, C, T);
    k_force<<<1024, 256, 0, stream>>>(xs, dws, T, Fr);
    k_out  <<<32, 128, 0, stream>>>(Fr, out);
}

// Round 14
// 209.499 us; speedup vs baseline: 2.0092x; 1.3850x over previous
//
#include <hip/hip_runtime.h>
#include <math.h>

#define NN 128
#define FF 64
#define KK 50
#define NTAB 1000
#define EPSV 1e-6f

// ws layout (floats):
// dws: [B*N*N]          off 0
// T:   [B*N*N]          off 524288
// A:   [(NTAB+1)*128]f4 off 1048576  (512512 floats, ends 1561088)  fwd table (G, hG')
// B:   [(NTAB+1)*128]f4 off 1561088  (512512 floats, ends 2073600)  bwd table (G', hG'')
// C:   [B*N*3*64]       off 2097152
// Fr:  [B*N*3]          off 2883584

__global__ __launch_bounds__(256) void k_dist(const float* __restrict__ xs, float* __restrict__ dws)
{
    int tid = blockIdx.x * 256 + threadIdx.x;
    int b = tid >> 14;
    int rem = tid & 16383;
    int i = rem >> 7, a = rem & 127;
    const float* xb = xs + b * (NN * 3);
    float dx = xb[i*3+0] - xb[a*3+0];
    float dy = xb[i*3+1] - xb[a*3+1];
    float dz = xb[i*3+2] - xb[a*3+2];
    dws[tid] = sqrtf(dx*dx + dy*dy + dz*dz + EPSV);
}

// radial tables, one thread per (node, f), double-precision build.
// A4: (G0,hG0',G1,hG1') (G2,hG2',0,0)   B4: (G0',hG0'',G1',hG1'') (G2',hG2'',0,0)
__global__ __launch_bounds__(256) void k_tab(
    const float* __restrict__ W1a, const float* __restrict__ W1b, const float* __restrict__ W1c,
    const float* __restrict__ b1a, const float* __restrict__ b1b, const float* __restrict__ b1c,
    const float* __restrict__ mus, const float* __restrict__ gamma,
    float4* __restrict__ A4, float4* __restrict__ B4)
{
    int idx = blockIdx.x * 256 + threadIdx.x;
    if (idx >= (NTAB + 1) * 64) return;
    int node = idx >> 6, f = idx & 63;
    double h = 10.0 / (double)NTAB;
    double d = (double)node * h;
    double gam = (double)gamma[0];
    const float* Ws[3] = { W1a, W1b, W1c };
    const float* bs[3] = { b1a, b1b, b1c };
    double Gd[3], Gpd[3], Gppd[3];
    for (int l = 0; l < 3; ++l) {
        double z = (double)bs[l][f], zp = 0.0, zpp = 0.0;
        for (int k = 0; k < KK; ++k) {
            double x = d - (double)mus[k];
            double e = exp(-gam * x * x);
            double we = (double)Ws[l][k * 64 + f] * e;
            z   += we;
            zp  += we * (-2.0 * gam * x);
            zpp += we * (4.0 * gam * gam * x * x - 2.0 * gam);
        }
        double sg = 1.0 / (1.0 + exp(-z));
        Gd[l]   = (z > 0.0) ? z + log1p(exp(-z)) : log1p(exp(z));
        Gpd[l]  = sg * zp;
        Gppd[l] = sg * (1.0 - sg) * zp * zp + sg * zpp;
    }
    int base = node * 128 + (f << 1);
    A4[base]     = make_float4((float)Gd[0],  (float)(h * Gpd[0]),  (float)Gd[1],  (float)(h * Gpd[1]));
    A4[base + 1] = make_float4((float)Gd[2],  (float)(h * Gpd[2]),  0.f, 0.f);
    B4[base]     = make_float4((float)Gpd[0], (float)(h * Gppd[0]), (float)Gpd[1], (float)(h * Gppd[1]));
    B4[base + 1] = make_float4((float)Gpd[2], (float)(h * Gppd[2]), 0.f, 0.f);
}

// ------- forward via packed table: 4 x b128 loads + Hermite per pair; fused epilogue -------
__global__ __launch_bounds__(512) void k_fwd(
    const float* __restrict__ dws, const float4* __restrict__ A4,
    const float* __restrict__ W2a, const float* __restrict__ W2b, const float* __restrict__ W2c,
    const float* __restrict__ b2a, const float* __restrict__ b2b, const float* __restrict__ b2c,
    const float* __restrict__ Wenc, const float* __restrict__ benc,
    const float* __restrict__ Wt1, const float* __restrict__ bt1, const float* __restrict__ Wt2,
    float* __restrict__ Cout)
{
    __shared__ double epid[8][FF];
    __shared__ float  epif[8][FF];

    int tid = threadIdx.x;
    int wave = tid >> 6, lane = tid & 63, f = lane;
    int atom = blockIdx.x * 8 + wave;
    int i = atom & 127;
    const float* drow = dws + (atom << 7);
    const float invh = (float)NTAB / 10.0f;
    double us0 = 0.0, us1 = 0.0, us2 = 0.0;

    #pragma unroll 1
    for (int t = 0; t < 8; ++t) {
        float ut0 = 0.f, ut1 = 0.f, ut2 = 0.f;
        #pragma unroll 4
        for (int p = 0; p < 16; ++p) {
            int pi = 16 * t + p;
            bool valid = pi < 127;
            float d = drow[(i + 1 + pi) & 127];
            float fd = fminf(d * invh, (float)NTAB - 0.001f);
            float jf = floorf(fd);
            float tt = fd - jf;
            int j = (int)jf;
            const float4* r0 = A4 + j * 128 + (f << 1);
            float4 u0 = r0[0],   u1 = r0[1];
            float4 v0 = r0[128], v1 = r0[129];
            float t2 = tt * tt, t3 = t2 * tt;
            float h00 = 2.f * t3 - 3.f * t2 + 1.f;
            float h01 = 1.f - h00;
            float h10 = t3 - 2.f * t2 + tt;
            float h11 = t3 - t2;
            float g0 = h00 * u0.x + h10 * u0.y + h01 * v0.x + h11 * v0.y;
            float g1 = h00 * u0.z + h10 * u0.w + h01 * v0.z + h11 * v0.w;
            float g2 = h00 * u1.x + h10 * u1.y + h01 * v1.x + h11 * v1.y;
            ut0 += valid ? g0 : 0.f;
            ut1 += valid ? g1 : 0.f;
            ut2 += valid ? g2 : 0.f;
        }
        us0 += (double)ut0; us1 += (double)ut1; us2 += (double)ut2;
    }

    // per-atom epilogue (wave-local, double precision for h/pre path)
    double wf0, wf1, wf2;
    {
        epid[wave][lane] = us0;
        double acc = 0.0;
        for (int m = 0; m < 64; ++m) acc += epid[wave][m] * (double)W2a[m*64 + f];
        wf0 = 1.0 + acc + 127.0 * (double)b2a[f];

        epid[wave][lane] = us1;
        double acc1 = 0.0;
        for (int m = 0; m < 64; ++m) acc1 += epid[wave][m] * (double)W2b[m*64 + f];
        wf1 = 1.0 + acc1 + 127.0 * (double)b2b[f];

        epid[wave][lane] = us2;
        double acc2 = 0.0;
        for (int m = 0; m < 64; ++m) acc2 += epid[wave][m] * (double)W2c[m*64 + f];
        wf2 = 1.0 + acc2 + 127.0 * (double)b2c[f];
    }
    double h0 = (double)Wenc[f] + (double)benc[f];
    double h  = h0 * wf0 * wf1 * wf2;
    epid[wave][lane] = h;
    double pre = (double)bt1[lane];
    for (int m = 0; m < 64; ++m) pre += epid[wave][m] * (double)Wt1[m*64 + lane];
    double tv = tanh(pre);
    float gv = (float)((1.0 - tv * tv) * (double)Wt2[lane]);

    float p1 = (float)(h0 * wf1 * wf2);
    float p2 = (float)(h0 * wf0 * wf2);
    float p3 = (float)(h0 * wf0 * wf1);

    epif[wave][lane] = gv;
    float dv = 0.f;
    for (int m = 0; m < 64; ++m) dv = fmaf(epif[wave][m], Wt1[lane*64 + m], dv);

    float* co = Cout + atom * 192;
    epif[wave][lane] = dv * p1;
    float c0 = 0.f;
    for (int m = 0; m < 64; ++m) c0 = fmaf(epif[wave][m], W2a[lane*64 + m], c0);
    co[lane] = c0;

    epif[wave][lane] = dv * p2;
    float c1 = 0.f;
    for (int m = 0; m < 64; ++m) c1 = fmaf(epif[wave][m], W2b[lane*64 + m], c1);
    co[64 + lane] = c1;

    epif[wave][lane] = dv * p3;
    float c2 = 0.f;
    for (int m = 0; m < 64; ++m) c2 = fmaf(epif[wave][m], W2c[lane*64 + m], c2);
    co[128 + lane] = c2;
}

// ------- backward via derivative table: per unordered pair 4 table loads + Hermite + contract -------
// wave = atom i; lane = f for the gathers/contraction; lane L holds result for offset L+1.
__global__ __launch_bounds__(256) void k_bwd(
    const float* __restrict__ dws, const float4* __restrict__ B4,
    const float* __restrict__ C, float* __restrict__ T)
{
    int tid = threadIdx.x;
    int wave = tid >> 6, lane = tid & 63;
    int atom = blockIdx.x * 4 + wave;
    int b = atom >> 7, i = atom & 127;
    const float* drow = dws + (atom << 7);
    const float* ci = C + atom * 192;
    float ci0 = ci[lane], ci1 = ci[64 + lane], ci2 = ci[128 + lane];
    float* Tb = T + ((size_t)b << 14);
    const float invh = (float)NTAB / 10.0f;
    float vm = 0.f;

    #pragma unroll 1
    for (int g = 0; g < 16; ++g) {
        int offb = 1 + (g << 2);
        float tt[4], cA[4], cB[4], cC[4];
        float4 u0[4], u1[4], v0[4], v1[4];
        int aa[4];
        #pragma unroll
        for (int p = 0; p < 4; ++p) {
            aa[p] = (i + offb + p) & 127;
            float d = drow[aa[p]];
            float fd = fminf(d * invh, (float)NTAB - 0.001f);
            float jf = floorf(fd);
            tt[p] = fd - jf;
            int j = (int)jf;
            const float4* r0 = B4 + j * 128 + (lane << 1);
            u0[p] = r0[0];   u1[p] = r0[1];
            v0[p] = r0[128]; v1[p] = r0[129];
            const float* ca = C + (((b << 7) + aa[p]) * 192);
            cA[p] = ca[lane]; cB[p] = ca[64 + lane]; cC[p] = ca[128 + lane];
        }
        #pragma unroll
        for (int p = 0; p < 4; ++p) {
            float t1 = tt[p], t2 = t1 * t1, t3 = t2 * t1;
            float h00 = 2.f * t3 - 3.f * t2 + 1.f;
            float h01 = 1.f - h00;
            float h10 = t3 - 2.f * t2 + t1;
            float h11 = t3 - t2;
            float g0 = h00 * u0[p].x + h10 * u0[p].y + h01 * v0[p].x + h11 * v0[p].y;
            float g1 = h00 * u0[p].z + h10 * u0[p].w + h01 * v0[p].z + h11 * v0[p].w;
            float g2 = h00 * u1[p].x + h10 * u1[p].y + h01 * v1[p].x + h11 * v1[p].y;
            float red = (ci0 + cA[p]) * g0 + (ci1 + cB[p]) * g1 + (ci2 + cC[p]) * g2;
            #pragma unroll
            for (int o = 1; o < 64; o <<= 1) red += __shfl_xor(red, o);
            if (lane == (g << 2) + p) vm = red;
        }
    }
    int off = lane + 1;
    if (off < 64 || i < 64) {
        int a = (i + off) & 127;
        Tb[(i << 7) + a] = vm;
        Tb[(a << 7) + i] = vm;
    }
}

__global__ __launch_bounds__(256) void k_force(
    const float* __restrict__ xs, const float* __restrict__ dws,
    const float* __restrict__ T, float* __restrict__ Fr)
{
    int tid = threadIdx.x;
    int wave = tid >> 6, lane = tid & 63;
    int atom = blockIdx.x * 4 + wave;
    int i = atom & 127;
    int b = atom >> 7;
    const float* xb = xs + b * (NN * 3);
    float xi0 = xb[i*3], xi1 = xb[i*3+1], xi2 = xb[i*3+2];
    const float* drow = dws + (atom << 7);
    const float* trow = T + (atom << 7);
    float fx = 0.f, fy = 0.f, fz = 0.f;
    for (int it = lane; it < 127; it += 64) {
        int aa = (i + 1 + it) & 127;
        float coef = trow[aa] / drow[aa];
        fx += coef * (xi0 - xb[aa*3]);
        fy += coef * (xi1 - xb[aa*3+1]);
        fz += coef * (xi2 - xb[aa*3+2]);
    }
    #pragma unroll
    for (int off = 1; off < 64; off <<= 1) {
        fx += __shfl_xor(fx, off);
        fy += __shfl_xor(fy, off);
        fz += __shfl_xor(fz, off);
    }
    if (lane == 0) {
        Fr[atom*3]   = fx;
        Fr[atom*3+1] = fy;
        Fr[atom*3+2] = fz;
    }
}

__global__ __launch_bounds__(128) void k_out(const float* __restrict__ Fr, float* __restrict__ out)
{
    __shared__ float rs[3][128];
    int b = blockIdx.x, n = threadIdx.x;
    float g0 = Fr[(b*128+n)*3], g1 = Fr[(b*128+n)*3+1], g2 = Fr[(b*128+n)*3+2];
    rs[0][n] = g0; rs[1][n] = g1; rs[2][n] = g2;
    __syncthreads();
    for (int s = 64; s > 0; s >>= 1) {
        if (n < s) {
            rs[0][n] += rs[0][n+s];
            rs[1][n] += rs[1][n+s];
            rs[2][n] += rs[2][n+s];
        }
        __syncthreads();
    }
    float m0 = rs[0][0] * (1.f/128.f);
    float m1 = rs[1][0] * (1.f/128.f);
    float m2 = rs[2][0] * (1.f/128.f);
    out[b*384 + n*3 + 0] = m0 - g0;
    out[b*384 + n*3 + 1] = m1 - g1;
    out[b*384 + n*3 + 2] = m2 - g2;
}

extern "C" void kernel_launch(void* const* d_in, const int* in_sizes, int n_in,
                              void* d_out, int out_size, void* d_ws, size_t ws_size,
                              hipStream_t stream)
{
    const float* xs   = (const float*)d_in[1];
    const float* mus  = (const float*)d_in[2];
    const float* gam  = (const float*)d_in[3];
    const float* Wenc = (const float*)d_in[4];
    const float* benc = (const float*)d_in[5];
    const float* W1a  = (const float*)d_in[6];
    const float* b1a  = (const float*)d_in[7];
    const float* W2a  = (const float*)d_in[8];
    const float* b2a  = (const float*)d_in[9];
    const float* W1b  = (const float*)d_in[10];
    const float* b1b  = (const float*)d_in[11];
    const float* W2b  = (const float*)d_in[12];
    const float* b2b  = (const float*)d_in[13];
    const float* W1c  = (const float*)d_in[14];
    const float* b1c  = (const float*)d_in[15];
    const float* W2c  = (const float*)d_in[16];
    const float* b2c  = (const float*)d_in[17];
    const float* Wt1  = (const float*)d_in[18];
    const float* bt1  = (const float*)d_in[19];
    const float* Wt2  = (const float*)d_in[20];

    float* ws  = (float*)d_ws;
    float* dws = ws;
    float* T   = ws + 524288;
    float4* A4 = (float4*)(ws + 1048576);
    float4* B4 = (float4*)(ws + 1561088);
    float* C   = ws + 2097152;
    float* Fr  = ws + 2883584;
    float* out = (float*)d_out;

    k_dist <<<2048, 256, 0, stream>>>(xs, dws);
    k_tab  <<<251, 256, 0, stream>>>(W1a, W1b, W1c, b1a, b1b, b1c, mus, gam, A4, B4);
    k_fwd  <<<512, 512, 0, stream>>>(dws, A4, W2a, W2b, W2c, b2a, b2b, b2c,
                                     Wenc, benc, Wt1, bt1, Wt2, C);
    k_bwd  <<<1024, 256, 0, stream>>>(dws, B4, C, T);
    k_force<<<1024, 256, 0, stream>>>(xs, dws, T, Fr);
    k_out  <<<32, 128, 0, stream>>>(Fr, out);
}

// Round 15
// 195.042 us; speedup vs baseline: 2.1581x; 1.0741x over previous
//
#include <hip/hip_runtime.h>
#include <math.h>

#define NN 128
#define FF 64
#define KK 50
#define NI 640               // intervals; h = 10/640
#define EPSV 1e-6f

// ws layout (floats):
// dws: [B*N*N]   off 0
// T:   [B*N*N]   off 524288
// A:   3 planes x NI*64 float4 = 491520 floats, off 1048576 (ends 1540096)  fwd cubic coeffs
// B:   same,                      off 1540096 (ends 2031616)                bwd cubic coeffs
// C:   [B*N*3*64] off 2097152
// Fr:  [B*N*3]    off 2883584

__global__ __launch_bounds__(256) void k_dist(const float* __restrict__ xs, float* __restrict__ dws)
{
    int tid = blockIdx.x * 256 + threadIdx.x;
    int b = tid >> 14;
    int rem = tid & 16383;
    int i = rem >> 7, a = rem & 127;
    const float* xb = xs + b * (NN * 3);
    float dx = xb[i*3+0] - xb[a*3+0];
    float dy = xb[i*3+1] - xb[a*3+1];
    float dz = xb[i*3+2] - xb[a*3+2];
    dws[tid] = sqrtf(dx*dx + dy*dy + dz*dz + EPSV);
}

// Per (interval, f): compute G, G', G'' at both endpoints (double) for the 3 layers,
// emit monomial coeffs of the Hermite cubic for fwd (G) and bwd (G') tables.
__global__ __launch_bounds__(256) void k_tab(
    const float* __restrict__ W1a, const float* __restrict__ W1b, const float* __restrict__ W1c,
    const float* __restrict__ b1a, const float* __restrict__ b1b, const float* __restrict__ b1c,
    const float* __restrict__ mus, const float* __restrict__ gamma,
    float4* __restrict__ Af, float4* __restrict__ Bf)
{
    int idx = blockIdx.x * 256 + threadIdx.x;   // NI*64 = 40960
    if (idx >= NI * 64) return;
    int j = idx >> 6, f = idx & 63;
    double h = 10.0 / (double)NI;
    double gam = (double)gamma[0];
    const float* Ws[3] = { W1a, W1b, W1c };
    const float* bs[3] = { b1a, b1b, b1c };
    for (int l = 0; l < 3; ++l) {
        double G[2], Gp[2], Gpp[2];
        for (int e = 0; e < 2; ++e) {
            double d = (double)(j + e) * h;
            double z = (double)bs[l][f], zp = 0.0, zpp = 0.0;
            for (int k = 0; k < KK; ++k) {
                double x = d - (double)mus[k];
                double ee = exp(-gam * x * x);
                double we = (double)Ws[l][k * 64 + f] * ee;
                z   += we;
                zp  += we * (-2.0 * gam * x);
                zpp += we * (4.0 * gam * gam * x * x - 2.0 * gam);
            }
            double sg = 1.0 / (1.0 + exp(-z));
            G[e]   = (z > 0.0) ? z + log1p(exp(-z)) : log1p(exp(z));
            Gp[e]  = sg * zp;
            Gpp[e] = sg * (1.0 - sg) * zp * zp + sg * zpp;
        }
        {
            double p0 = G[0], m0 = h * Gp[0], p1 = G[1], m1 = h * Gp[1];
            Af[l * (NI * 64) + idx] = make_float4(
                (float)p0, (float)m0,
                (float)(3.0 * (p1 - p0) - 2.0 * m0 - m1),
                (float)(2.0 * (p0 - p1) + m0 + m1));
        }
        {
            double q0 = Gp[0], n0 = h * Gpp[0], q1 = Gp[1], n1 = h * Gpp[1];
            Bf[l * (NI * 64) + idx] = make_float4(
                (float)q0, (float)n0,
                (float)(3.0 * (q1 - q0) - 2.0 * n0 - n1),
                (float)(2.0 * (q0 - q1) + n0 + n1));
        }
    }
}

// ------- forward via coefficient table: 3 coalesced b128 + Horner per pair; fused epilogue -------
__global__ __launch_bounds__(512) void k_fwd(
    const float* __restrict__ dws, const float4* __restrict__ A4,
    const float* __restrict__ W2a, const float* __restrict__ W2b, const float* __restrict__ W2c,
    const float* __restrict__ b2a, const float* __restrict__ b2b, const float* __restrict__ b2c,
    const float* __restrict__ Wenc, const float* __restrict__ benc,
    const float* __restrict__ Wt1, const float* __restrict__ bt1, const float* __restrict__ Wt2,
    float* __restrict__ Cout)
{
    __shared__ double epid[8][FF];
    __shared__ float  epif[8][FF];

    int tid = threadIdx.x;
    int wave = tid >> 6, lane = tid & 63, f = lane;
    int atom = blockIdx.x * 8 + wave;
    int i = atom & 127;
    const float* drow = dws + (atom << 7);
    const float invh = (float)NI / 10.0f;
    double us0 = 0.0, us1 = 0.0, us2 = 0.0;

    #pragma unroll 1
    for (int t = 0; t < 8; ++t) {
        float ut0 = 0.f, ut1 = 0.f, ut2 = 0.f;
        #pragma unroll 4
        for (int p = 0; p < 16; ++p) {
            int pi = 16 * t + p;
            bool valid = pi < 127;
            float d = drow[(i + 1 + pi) & 127];
            float fd = fminf(d * invh, (float)NI - 0.001f);
            float jf = floorf(fd);
            float tt = fd - jf;
            int j4 = (int)jf * 64 + f;
            float4 c0 = A4[j4];
            float4 c1 = A4[NI * 64 + j4];
            float4 c2 = A4[2 * NI * 64 + j4];
            float g0 = fmaf(tt, fmaf(tt, fmaf(tt, c0.w, c0.z), c0.y), c0.x);
            float g1 = fmaf(tt, fmaf(tt, fmaf(tt, c1.w, c1.z), c1.y), c1.x);
            float g2 = fmaf(tt, fmaf(tt, fmaf(tt, c2.w, c2.z), c2.y), c2.x);
            ut0 += valid ? g0 : 0.f;
            ut1 += valid ? g1 : 0.f;
            ut2 += valid ? g2 : 0.f;
        }
        us0 += (double)ut0; us1 += (double)ut1; us2 += (double)ut2;
    }

    // per-atom epilogue (wave-local, double precision for h/pre path)
    double wf0, wf1, wf2;
    {
        epid[wave][lane] = us0;
        double acc = 0.0;
        for (int m = 0; m < 64; ++m) acc += epid[wave][m] * (double)W2a[m*64 + f];
        wf0 = 1.0 + acc + 127.0 * (double)b2a[f];

        epid[wave][lane] = us1;
        double acc1 = 0.0;
        for (int m = 0; m < 64; ++m) acc1 += epid[wave][m] * (double)W2b[m*64 + f];
        wf1 = 1.0 + acc1 + 127.0 * (double)b2b[f];

        epid[wave][lane] = us2;
        double acc2 = 0.0;
        for (int m = 0; m < 64; ++m) acc2 += epid[wave][m] * (double)W2c[m*64 + f];
        wf2 = 1.0 + acc2 + 127.0 * (double)b2c[f];
    }
    double h0 = (double)Wenc[f] + (double)benc[f];
    double h  = h0 * wf0 * wf1 * wf2;
    epid[wave][lane] = h;
    double pre = (double)bt1[lane];
    for (int m = 0; m < 64; ++m) pre += epid[wave][m] * (double)Wt1[m*64 + lane];
    double tv = tanh(pre);
    float gv = (float)((1.0 - tv * tv) * (double)Wt2[lane]);

    float p1 = (float)(h0 * wf1 * wf2);
    float p2 = (float)(h0 * wf0 * wf2);
    float p3 = (float)(h0 * wf0 * wf1);

    epif[wave][lane] = gv;
    float dv = 0.f;
    for (int m = 0; m < 64; ++m) dv = fmaf(epif[wave][m], Wt1[lane*64 + m], dv);

    float* co = Cout + atom * 192;
    epif[wave][lane] = dv * p1;
    float c0 = 0.f;
    for (int m = 0; m < 64; ++m) c0 = fmaf(epif[wave][m], W2a[lane*64 + m], c0);
    co[lane] = c0;

    epif[wave][lane] = dv * p2;
    float c1 = 0.f;
    for (int m = 0; m < 64; ++m) c1 = fmaf(epif[wave][m], W2b[lane*64 + m], c1);
    co[64 + lane] = c1;

    epif[wave][lane] = dv * p3;
    float c2 = 0.f;
    for (int m = 0; m < 64; ++m) c2 = fmaf(epif[wave][m], W2c[lane*64 + m], c2);
    co[128 + lane] = c2;
}

// ------- backward via derivative coefficient table -------
__global__ __launch_bounds__(256) void k_bwd(
    const float* __restrict__ dws, const float4* __restrict__ B4,
    const float* __restrict__ C, float* __restrict__ T)
{
    int tid = threadIdx.x;
    int wave = tid >> 6, lane = tid & 63;
    int atom = blockIdx.x * 4 + wave;
    int b = atom >> 7, i = atom & 127;
    const float* drow = dws + (atom << 7);
    const float* ci = C + atom * 192;
    float ci0 = ci[lane], ci1 = ci[64 + lane], ci2 = ci[128 + lane];
    float* Tb = T + ((size_t)b << 14);
    const float invh = (float)NI / 10.0f;
    float vm = 0.f;

    #pragma unroll 1
    for (int g = 0; g < 16; ++g) {
        int offb = 1 + (g << 2);
        float tt[4], cA[4], cB[4], cC[4];
        float4 u0[4], u1[4], u2[4];
        #pragma unroll
        for (int p = 0; p < 4; ++p) {
            int aa = (i + offb + p) & 127;
            float d = drow[aa];
            float fd = fminf(d * invh, (float)NI - 0.001f);
            float jf = floorf(fd);
            tt[p] = fd - jf;
            int j4 = (int)jf * 64 + lane;
            u0[p] = B4[j4];
            u1[p] = B4[NI * 64 + j4];
            u2[p] = B4[2 * NI * 64 + j4];
            const float* ca = C + (((b << 7) + aa) * 192);
            cA[p] = ca[lane]; cB[p] = ca[64 + lane]; cC[p] = ca[128 + lane];
        }
        #pragma unroll
        for (int p = 0; p < 4; ++p) {
            float t1 = tt[p];
            float g0 = fmaf(t1, fmaf(t1, fmaf(t1, u0[p].w, u0[p].z), u0[p].y), u0[p].x);
            float g1 = fmaf(t1, fmaf(t1, fmaf(t1, u1[p].w, u1[p].z), u1[p].y), u1[p].x);
            float g2 = fmaf(t1, fmaf(t1, fmaf(t1, u2[p].w, u2[p].z), u2[p].y), u2[p].x);
            float red = (ci0 + cA[p]) * g0 + (ci1 + cB[p]) * g1 + (ci2 + cC[p]) * g2;
            #pragma unroll
            for (int o = 1; o < 64; o <<= 1) red += __shfl_xor(red, o);
            if (lane == (g << 2) + p) vm = red;
        }
    }
    int off = lane + 1;
    if (off < 64 || i < 64) {
        int a = (i + off) & 127;
        Tb[(i << 7) + a] = vm;
        Tb[(a << 7) + i] = vm;
    }
}

__global__ __launch_bounds__(256) void k_force(
    const float* __restrict__ xs, const float* __restrict__ dws,
    const float* __restrict__ T, float* __restrict__ Fr)
{
    int tid = threadIdx.x;
    int wave = tid >> 6, lane = tid & 63;
    int atom = blockIdx.x * 4 + wave;
    int i = atom & 127;
    int b = atom >> 7;
    const float* xb = xs + b * (NN * 3);
    float xi0 = xb[i*3], xi1 = xb[i*3+1], xi2 = xb[i*3+2];
    const float* drow = dws + (atom << 7);
    const float* trow = T + (atom << 7);
    float fx = 0.f, fy = 0.f, fz = 0.f;
    for (int it = lane; it < 127; it += 64) {
        int aa = (i + 1 + it) & 127;
        float coef = trow[aa] / drow[aa];
        fx += coef * (xi0 - xb[aa*3]);
        fy += coef * (xi1 - xb[aa*3+1]);
        fz += coef * (xi2 - xb[aa*3+2]);
    }
    #pragma unroll
    for (int off = 1; off < 64; off <<= 1) {
        fx += __shfl_xor(fx, off);
        fy += __shfl_xor(fy, off);
        fz += __shfl_xor(fz, off);
    }
    if (lane == 0) {
        Fr[atom*3]   = fx;
        Fr[atom*3+1] = fy;
        Fr[atom*3+2] = fz;
    }
}

__global__ __launch_bounds__(128) void k_out(const float* __restrict__ Fr, float* __restrict__ out)
{
    __shared__ float rs[3][128];
    int b = blockIdx.x, n = threadIdx.x;
    float g0 = Fr[(b*128+n)*3], g1 = Fr[(b*128+n)*3+1], g2 = Fr[(b*128+n)*3+2];
    rs[0][n] = g0; rs[1][n] = g1; rs[2][n] = g2;
    __syncthreads();
    for (int s = 64; s > 0; s >>= 1) {
        if (n < s) {
            rs[0][n] += rs[0][n+s];
            rs[1][n] += rs[1][n+s];
            rs[2][n] += rs[2][n+s];
        }
        __syncthreads();
    }
    float m0 = rs[0][0] * (1.f/128.f);
    float m1 = rs[1][0] * (1.f/128.f);
    float m2 = rs[2][0] * (1.f/128.f);
    out[b*384 + n*3 + 0] = m0 - g0;
    out[b*384 + n*3 + 1] = m1 - g1;
    out[b*384 + n*3 + 2] = m2 - g2;
}

extern "C" void kernel_launch(void* const* d_in, const int* in_sizes, int n_in,
                              void* d_out, int out_size, void* d_ws, size_t ws_size,
                              hipStream_t stream)
{
    const float* xs   = (const float*)d_in[1];
    const float* mus  = (const float*)d_in[2];
    const float* gam  = (const float*)d_in[3];
    const float* Wenc = (const float*)d_in[4];
    const float* benc = (const float*)d_in[5];
    const float* W1a  = (const float*)d_in[6];
    const float* b1a  = (const float*)d_in[7];
    const float* W2a  = (const float*)d_in[8];
    const float* b2a  = (const float*)d_in[9];
    const float* W1b  = (const float*)d_in[10];
    const float* b1b  = (const float*)d_in[11];
    const float* W2b  = (const float*)d_in[12];
    const float* b2b  = (const float*)d_in[13];
    const float* W1c  = (const float*)d_in[14];
    const float* b1c  = (const float*)d_in[15];
    const float* W2c  = (const float*)d_in[16];
    const float* b2c  = (const float*)d_in[17];
    const float* Wt1  = (const float*)d_in[18];
    const float* bt1  = (const float*)d_in[19];
    const float* Wt2  = (const float*)d_in[20];

    float* ws  = (float*)d_ws;
    float* dws = ws;
    float* T   = ws + 524288;
    float4* A4 = (float4*)(ws + 1048576);
    float4* B4 = (float4*)(ws + 1540096);
    float* C   = ws + 2097152;
    float* Fr  = ws + 2883584;
    float* out = (float*)d_out;

    k_dist <<<2048, 256, 0, stream>>>(xs, dws);
    k_tab  <<<160, 256, 0, stream>>>(W1a, W1b, W1c, b1a, b1b, b1c, mus, gam, A4, B4);
    k_fwd  <<<512, 512, 0, stream>>>(dws, A4, W2a, W2b, W2c, b2a, b2b, b2c,
                                     Wenc, benc, Wt1, bt1, Wt2, C);
    k_bwd  <<<1024, 256, 0, stream>>>(dws, B4, C, T);
    k_force<<<1024, 256, 0, stream>>>(xs, dws, T, Fr);
    k_out  <<<32, 128, 0, stream>>>(Fr, out);
}

// Round 16
// 184.791 us; speedup vs baseline: 2.2779x; 1.0555x over previous
//
#include <hip/hip_runtime.h>
#include <math.h>

#define NN 128
#define FF 64
#define KK 50
#define NI 640               // intervals; h = 10/640
#define EPSV 1e-6f

// ws layout (floats):
// dws: [B*N*N]   off 0
// T:   [B*N*N]   off 524288
// A:   3 planes x NI*64 float4 = 491520 floats, off 1048576 (ends 1540096)  fwd cubic coeffs
// B:   same,                      off 1540096 (ends 2031616)                bwd cubic coeffs
// C:   [B*N*3*64] off 2097152
// Fr:  [B*N*3]    off 2883584

__global__ __launch_bounds__(256) void k_dist(const float* __restrict__ xs, float* __restrict__ dws)
{
    int tid = blockIdx.x * 256 + threadIdx.x;
    int b = tid >> 14;
    int rem = tid & 16383;
    int i = rem >> 7, a = rem & 127;
    const float* xb = xs + b * (NN * 3);
    float dx = xb[i*3+0] - xb[a*3+0];
    float dy = xb[i*3+1] - xb[a*3+1];
    float dz = xb[i*3+2] - xb[a*3+2];
    dws[tid] = sqrtf(dx*dx + dy*dy + dz*dz + EPSV);
}

// Per (interval, f): compute G, G', G'' at both endpoints (double) for the 3 layers,
// emit monomial coeffs of the Hermite cubic for fwd (G) and bwd (G') tables.
__global__ __launch_bounds__(256) void k_tab(
    const float* __restrict__ W1a, const float* __restrict__ W1b, const float* __restrict__ W1c,
    const float* __restrict__ b1a, const float* __restrict__ b1b, const float* __restrict__ b1c,
    const float* __restrict__ mus, const float* __restrict__ gamma,
    float4* __restrict__ Af, float4* __restrict__ Bf)
{
    int idx = blockIdx.x * 256 + threadIdx.x;   // NI*64 = 40960
    if (idx >= NI * 64) return;
    int j = idx >> 6, f = idx & 63;
    double h = 10.0 / (double)NI;
    double gam = (double)gamma[0];
    const float* Ws[3] = { W1a, W1b, W1c };
    const float* bs[3] = { b1a, b1b, b1c };
    for (int l = 0; l < 3; ++l) {
        double G[2], Gp[2], Gpp[2];
        for (int e = 0; e < 2; ++e) {
            double d = (double)(j + e) * h;
            double z = (double)bs[l][f], zp = 0.0, zpp = 0.0;
            for (int k = 0; k < KK; ++k) {
                double x = d - (double)mus[k];
                double ee = exp(-gam * x * x);
                double we = (double)Ws[l][k * 64 + f] * ee;
                z   += we;
                zp  += we * (-2.0 * gam * x);
                zpp += we * (4.0 * gam * gam * x * x - 2.0 * gam);
            }
            double sg = 1.0 / (1.0 + exp(-z));
            G[e]   = (z > 0.0) ? z + log1p(exp(-z)) : log1p(exp(z));
            Gp[e]  = sg * zp;
            Gpp[e] = sg * (1.0 - sg) * zp * zp + sg * zpp;
        }
        {
            double p0 = G[0], m0 = h * Gp[0], p1 = G[1], m1 = h * Gp[1];
            Af[l * (NI * 64) + idx] = make_float4(
                (float)p0, (float)m0,
                (float)(3.0 * (p1 - p0) - 2.0 * m0 - m1),
                (float)(2.0 * (p0 - p1) + m0 + m1));
        }
        {
            double q0 = Gp[0], n0 = h * Gpp[0], q1 = Gp[1], n1 = h * Gpp[1];
            Bf[l * (NI * 64) + idx] = make_float4(
                (float)q0, (float)n0,
                (float)(3.0 * (q1 - q0) - 2.0 * n0 - n1),
                (float)(2.0 * (q0 - q1) + n0 + n1));
        }
    }
}

// ------- forward: d-row in LDS, 3 coalesced b128 + Horner per pair; fused epilogue -------
__global__ __launch_bounds__(256) void k_fwd(
    const float* __restrict__ dws, const float4* __restrict__ A4,
    const float* __restrict__ W2a, const float* __restrict__ W2b, const float* __restrict__ W2c,
    const float* __restrict__ b2a, const float* __restrict__ b2b, const float* __restrict__ b2c,
    const float* __restrict__ Wenc, const float* __restrict__ benc,
    const float* __restrict__ Wt1, const float* __restrict__ bt1, const float* __restrict__ Wt2,
    float* __restrict__ Cout)
{
    __shared__ float  dsh[4][128];
    __shared__ double epid[4][FF];
    __shared__ float  epif[4][FF];

    int tid = threadIdx.x;
    int wave = tid >> 6, lane = tid & 63, f = lane;
    int atom = blockIdx.x * 4 + wave;
    int i = atom & 127;
    const float* drow = dws + (atom << 7);
    dsh[wave][lane]      = drow[lane];
    dsh[wave][64 + lane] = drow[64 + lane];
    const float invh = (float)NI / 10.0f;
    double us0 = 0.0, us1 = 0.0, us2 = 0.0;

    #pragma unroll 1
    for (int t = 0; t < 8; ++t) {
        float ut0 = 0.f, ut1 = 0.f, ut2 = 0.f;
        #pragma unroll 4
        for (int p = 0; p < 16; ++p) {
            int pi = 16 * t + p;
            bool valid = pi < 127;
            float d = dsh[wave][(i + 1 + pi) & 127];
            float fd = fminf(d * invh, (float)NI - 0.001f);
            float jf = floorf(fd);
            float tt = fd - jf;
            int j4 = (int)jf * 64 + f;
            float4 c0 = A4[j4];
            float4 c1 = A4[NI * 64 + j4];
            float4 c2 = A4[2 * NI * 64 + j4];
            float g0 = fmaf(tt, fmaf(tt, fmaf(tt, c0.w, c0.z), c0.y), c0.x);
            float g1 = fmaf(tt, fmaf(tt, fmaf(tt, c1.w, c1.z), c1.y), c1.x);
            float g2 = fmaf(tt, fmaf(tt, fmaf(tt, c2.w, c2.z), c2.y), c2.x);
            ut0 += valid ? g0 : 0.f;
            ut1 += valid ? g1 : 0.f;
            ut2 += valid ? g2 : 0.f;
        }
        us0 += (double)ut0; us1 += (double)ut1; us2 += (double)ut2;
    }

    // per-atom epilogue (wave-local, double precision for h/pre path)
    double wf0, wf1, wf2;
    {
        epid[wave][lane] = us0;
        double acc = 0.0;
        for (int m = 0; m < 64; ++m) acc += epid[wave][m] * (double)W2a[m*64 + f];
        wf0 = 1.0 + acc + 127.0 * (double)b2a[f];

        epid[wave][lane] = us1;
        double acc1 = 0.0;
        for (int m = 0; m < 64; ++m) acc1 += epid[wave][m] * (double)W2b[m*64 + f];
        wf1 = 1.0 + acc1 + 127.0 * (double)b2b[f];

        epid[wave][lane] = us2;
        double acc2 = 0.0;
        for (int m = 0; m < 64; ++m) acc2 += epid[wave][m] * (double)W2c[m*64 + f];
        wf2 = 1.0 + acc2 + 127.0 * (double)b2c[f];
    }
    double h0 = (double)Wenc[f] + (double)benc[f];
    double h  = h0 * wf0 * wf1 * wf2;
    epid[wave][lane] = h;
    double pre = (double)bt1[lane];
    for (int m = 0; m < 64; ++m) pre += epid[wave][m] * (double)Wt1[m*64 + lane];
    double tv = tanh(pre);
    float gv = (float)((1.0 - tv * tv) * (double)Wt2[lane]);

    float p1 = (float)(h0 * wf1 * wf2);
    float p2 = (float)(h0 * wf0 * wf2);
    float p3 = (float)(h0 * wf0 * wf1);

    epif[wave][lane] = gv;
    float dv = 0.f;
    for (int m = 0; m < 64; ++m) dv = fmaf(epif[wave][m], Wt1[lane*64 + m], dv);

    float* co = Cout + atom * 192;
    epif[wave][lane] = dv * p1;
    float c0 = 0.f;
    for (int m = 0; m < 64; ++m) c0 = fmaf(epif[wave][m], W2a[lane*64 + m], c0);
    co[lane] = c0;

    epif[wave][lane] = dv * p2;
    float c1 = 0.f;
    for (int m = 0; m < 64; ++m) c1 = fmaf(epif[wave][m], W2b[lane*64 + m], c1);
    co[64 + lane] = c1;

    epif[wave][lane] = dv * p3;
    float c2 = 0.f;
    for (int m = 0; m < 64; ++m) c2 = fmaf(epif[wave][m], W2c[lane*64 + m], c2);
    co[128 + lane] = c2;
}

// ------- backward via derivative coefficient table, d-row in LDS -------
__global__ __launch_bounds__(256) void k_bwd(
    const float* __restrict__ dws, const float4* __restrict__ B4,
    const float* __restrict__ C, float* __restrict__ T)
{
    __shared__ float dsh[4][128];
    int tid = threadIdx.x;
    int wave = tid >> 6, lane = tid & 63;
    int atom = blockIdx.x * 4 + wave;
    int b = atom >> 7, i = atom & 127;
    const float* drow = dws + (atom << 7);
    dsh[wave][lane]      = drow[lane];
    dsh[wave][64 + lane] = drow[64 + lane];
    const float* ci = C + atom * 192;
    float ci0 = ci[lane], ci1 = ci[64 + lane], ci2 = ci[128 + lane];
    float* Tb = T + ((size_t)b << 14);
    const float invh = (float)NI / 10.0f;
    float vm = 0.f;

    #pragma unroll 1
    for (int g = 0; g < 16; ++g) {
        int offb = 1 + (g << 2);
        float tt[4], cA[4], cB[4], cC[4];
        float4 u0[4], u1[4], u2[4];
        #pragma unroll
        for (int p = 0; p < 4; ++p) {
            int aa = (i + offb + p) & 127;
            float d = dsh[wave][aa];
            float fd = fminf(d * invh, (float)NI - 0.001f);
            float jf = floorf(fd);
            tt[p] = fd - jf;
            int j4 = (int)jf * 64 + lane;
            u0[p] = B4[j4];
            u1[p] = B4[NI * 64 + j4];
            u2[p] = B4[2 * NI * 64 + j4];
            const float* ca = C + (((b << 7) + aa) * 192);
            cA[p] = ca[lane]; cB[p] = ca[64 + lane]; cC[p] = ca[128 + lane];
        }
        #pragma unroll
        for (int p = 0; p < 4; ++p) {
            float t1 = tt[p];
            float g0 = fmaf(t1, fmaf(t1, fmaf(t1, u0[p].w, u0[p].z), u0[p].y), u0[p].x);
            float g1 = fmaf(t1, fmaf(t1, fmaf(t1, u1[p].w, u1[p].z), u1[p].y), u1[p].x);
            float g2 = fmaf(t1, fmaf(t1, fmaf(t1, u2[p].w, u2[p].z), u2[p].y), u2[p].x);
            float red = (ci0 + cA[p]) * g0 + (ci1 + cB[p]) * g1 + (ci2 + cC[p]) * g2;
            #pragma unroll
            for (int o = 1; o < 64; o <<= 1) red += __shfl_xor(red, o);
            if (lane == (g << 2) + p) vm = red;
        }
    }
    int off = lane + 1;
    if (off < 64 || i < 64) {
        int a = (i + off) & 127;
        Tb[(i << 7) + a] = vm;
        Tb[(a << 7) + i] = vm;
    }
}

__global__ __launch_bounds__(256) void k_force(
    const float* __restrict__ xs, const float* __restrict__ dws,
    const float* __restrict__ T, float* __restrict__ Fr)
{
    int tid = threadIdx.x;
    int wave = tid >> 6, lane = tid & 63;
    int atom = blockIdx.x * 4 + wave;
    int i = atom & 127;
    int b = atom >> 7;
    const float* xb = xs + b * (NN * 3);
    float xi0 = xb[i*3], xi1 = xb[i*3+1], xi2 = xb[i*3+2];
    const float* drow = dws + (atom << 7);
    const float* trow = T + (atom << 7);
    float fx = 0.f, fy = 0.f, fz = 0.f;
    for (int it = lane; it < 127; it += 64) {
        int aa = (i + 1 + it) & 127;
        float coef = trow[aa] / drow[aa];
        fx += coef * (xi0 - xb[aa*3]);
        fy += coef * (xi1 - xb[aa*3+1]);
        fz += coef * (xi2 - xb[aa*3+2]);
    }
    #pragma unroll
    for (int off = 1; off < 64; off <<= 1) {
        fx += __shfl_xor(fx, off);
        fy += __shfl_xor(fy, off);
        fz += __shfl_xor(fz, off);
    }
    if (lane == 0) {
        Fr[atom*3]   = fx;
        Fr[atom*3+1] = fy;
        Fr[atom*3+2] = fz;
    }
}

__global__ __launch_bounds__(128) void k_out(const float* __restrict__ Fr, float* __restrict__ out)
{
    __shared__ float rs[3][128];
    int b = blockIdx.x, n = threadIdx.x;
    float g0 = Fr[(b*128+n)*3], g1 = Fr[(b*128+n)*3+1], g2 = Fr[(b*128+n)*3+2];
    rs[0][n] = g0; rs[1][n] = g1; rs[2][n] = g2;
    __syncthreads();
    for (int s = 64; s > 0; s >>= 1) {
        if (n < s) {
            rs[0][n] += rs[0][n+s];
            rs[1][n] += rs[1][n+s];
            rs[2][n] += rs[2][n+s];
        }
        __syncthreads();
    }
    float m0 = rs[0][0] * (1.f/128.f);
    float m1 = rs[1][0] * (1.f/128.f);
    float m2 = rs[2][0] * (1.f/128.f);
    out[b*384 + n*3 + 0] = m0 - g0;
    out[b*384 + n*3 + 1] = m1 - g1;
    out[b*384 + n*3 + 2] = m2 - g2;
}

extern "C" void kernel_launch(void* const* d_in, const int* in_sizes, int n_in,
                              void* d_out, int out_size, void* d_ws, size_t ws_size,
                              hipStream_t stream)
{
    const float* xs   = (const float*)d_in[1];
    const float* mus  = (const float*)d_in[2];
    const float* gam  = (const float*)d_in[3];
    const float* Wenc = (const float*)d_in[4];
    const float* benc = (const float*)d_in[5];
    const float* W1a  = (const float*)d_in[6];
    const float* b1a  = (const float*)d_in[7];
    const float* W2a  = (const float*)d_in[8];
    const float* b2a  = (const float*)d_in[9];
    const float* W1b  = (const float*)d_in[10];
    const float* b1b  = (const float*)d_in[11];
    const float* W2b  = (const float*)d_in[12];
    const float* b2b  = (const float*)d_in[13];
    const float* W1c  = (const float*)d_in[14];
    const float* b1c  = (const float*)d_in[15];
    const float* W2c  = (const float*)d_in[16];
    const float* b2c  = (const float*)d_in[17];
    const float* Wt1  = (const float*)d_in[18];
    const float* bt1  = (const float*)d_in[19];
    const float* Wt2  = (const float*)d_in[20];

    float* ws  = (float*)d_ws;
    float* dws = ws;
    float* T   = ws + 524288;
    float4* A4 = (float4*)(ws + 1048576);
    float4* B4 = (float4*)(ws + 1540096);
    float* C   = ws + 2097152;
    float* Fr  = ws + 2883584;
    float* out = (float*)d_out;

    k_dist <<<2048, 256, 0, stream>>>(xs, dws);
    k_tab  <<<160, 256, 0, stream>>>(W1a, W1b, W1c, b1a, b1b, b1c, mus, gam, A4, B4);
    k_fwd  <<<1024, 256, 0, stream>>>(dws, A4, W2a, W2b, W2c, b2a, b2b, b2c,
                                      Wenc, benc, Wt1, bt1, Wt2, C);
    k_bwd  <<<1024, 256, 0, stream>>>(dws, B4, C, T);
    k_force<<<1024, 256, 0, stream>>>(xs, dws, T, Fr);
    k_out  <<<32, 128, 0, stream>>>(Fr, out);
}

// Round 17
// 181.259 us; speedup vs baseline: 2.3222x; 1.0195x over previous
//
#include <hip/hip_runtime.h>
#include <math.h>

#define NN 128
#define FF 64
#define KK 50
#define NI 640               // intervals; h = 10/640
#define EPSV 1e-6f

// ws layout (floats):
// dws: [B*N*N]   off 0
// T:   [B*N*N]   off 524288
// A:   3 planes x NI*64 float4 = 491520 floats, off 1048576 (ends 1540096)  fwd cubic coeffs
// B:   same,                      off 1540096 (ends 2031616)                bwd cubic coeffs
// C:   [B*N*3*64] off 2097152
// Fr:  [B*N*3]    off 2883584

// fused: blocks [0,2048) compute pair distances; blocks [2048, 2208) build tables
__global__ __launch_bounds__(256) void k_dt(
    const float* __restrict__ xs, float* __restrict__ dws,
    const float* __restrict__ W1a, const float* __restrict__ W1b, const float* __restrict__ W1c,
    const float* __restrict__ b1a, const float* __restrict__ b1b, const float* __restrict__ b1c,
    const float* __restrict__ mus, const float* __restrict__ gamma,
    float4* __restrict__ Af, float4* __restrict__ Bf)
{
    int bid = blockIdx.x;
    if (bid < 2048) {
        int tid = bid * 256 + threadIdx.x;
        int b = tid >> 14;
        int rem = tid & 16383;
        int i = rem >> 7, a = rem & 127;
        const float* xb = xs + b * (NN * 3);
        float dx = xb[i*3+0] - xb[a*3+0];
        float dy = xb[i*3+1] - xb[a*3+1];
        float dz = xb[i*3+2] - xb[a*3+2];
        dws[tid] = sqrtf(dx*dx + dy*dy + dz*dz + EPSV);
        return;
    }
    int idx = (bid - 2048) * 256 + threadIdx.x;   // NI*64 = 40960
    if (idx >= NI * 64) return;
    int j = idx >> 6, f = idx & 63;
    double h = 10.0 / (double)NI;
    double gam = (double)gamma[0];
    const float* Ws[3] = { W1a, W1b, W1c };
    const float* bs[3] = { b1a, b1b, b1c };
    for (int l = 0; l < 3; ++l) {
        double G[2], Gp[2], Gpp[2];
        for (int e = 0; e < 2; ++e) {
            double d = (double)(j + e) * h;
            double z = (double)bs[l][f], zp = 0.0, zpp = 0.0;
            for (int k = 0; k < KK; ++k) {
                double x = d - (double)mus[k];
                double ee = exp(-gam * x * x);
                double we = (double)Ws[l][k * 64 + f] * ee;
                z   += we;
                zp  += we * (-2.0 * gam * x);
                zpp += we * (4.0 * gam * gam * x * x - 2.0 * gam);
            }
            double sg = 1.0 / (1.0 + exp(-z));
            G[e]   = (z > 0.0) ? z + log1p(exp(-z)) : log1p(exp(z));
            Gp[e]  = sg * zp;
            Gpp[e] = sg * (1.0 - sg) * zp * zp + sg * zpp;
        }
        {
            double p0 = G[0], m0 = h * Gp[0], p1 = G[1], m1 = h * Gp[1];
            Af[l * (NI * 64) + idx] = make_float4(
                (float)p0, (float)m0,
                (float)(3.0 * (p1 - p0) - 2.0 * m0 - m1),
                (float)(2.0 * (p0 - p1) + m0 + m1));
        }
        {
            double q0 = Gp[0], n0 = h * Gpp[0], q1 = Gp[1], n1 = h * Gpp[1];
            Bf[l * (NI * 64) + idx] = make_float4(
                (float)q0, (float)n0,
                (float)(3.0 * (q1 - q0) - 2.0 * n0 - n1),
                (float)(2.0 * (q0 - q1) + n0 + n1));
        }
    }
}

// ------- forward: d-row in LDS, maskless 32-pair groups, unroll 8; fused epilogue -------
__global__ __launch_bounds__(256) void k_fwd(
    const float* __restrict__ dws, const float4* __restrict__ A4,
    const float* __restrict__ W2a, const float* __restrict__ W2b, const float* __restrict__ W2c,
    const float* __restrict__ b2a, const float* __restrict__ b2b, const float* __restrict__ b2c,
    const float* __restrict__ Wenc, const float* __restrict__ benc,
    const float* __restrict__ Wt1, const float* __restrict__ bt1, const float* __restrict__ Wt2,
    float* __restrict__ Cout)
{
    __shared__ float  dsh[4][128];
    __shared__ double epid[4][FF];
    __shared__ float  epif[4][FF];

    int tid = threadIdx.x;
    int wave = tid >> 6, lane = tid & 63, f = lane;
    int atom = blockIdx.x * 4 + wave;
    int i = atom & 127;
    const float* drow = dws + (atom << 7);
    dsh[wave][lane]      = drow[lane];
    dsh[wave][64 + lane] = drow[64 + lane];
    const float invh = (float)NI / 10.0f;
    const float4* Afp = A4 + f;
    double us0 = 0.0, us1 = 0.0, us2 = 0.0;
    float ut0, ut1, ut2;

    #define PAIR_BODY(PI)                                                   \
        {                                                                   \
            float d = dsh[wave][(i + 1 + (PI)) & 127];                      \
            float fd = fminf(d * invh, (float)NI - 0.001f);                 \
            float jf = floorf(fd);                                          \
            float tt = fd - jf;                                             \
            int j4 = (int)jf << 6;                                          \
            float4 c0 = Afp[j4];                                            \
            float4 c1 = Afp[NI * 64 + j4];                                  \
            float4 c2 = Afp[2 * NI * 64 + j4];                              \
            ut0 += fmaf(tt, fmaf(tt, fmaf(tt, c0.w, c0.z), c0.y), c0.x);    \
            ut1 += fmaf(tt, fmaf(tt, fmaf(tt, c1.w, c1.z), c1.y), c1.x);    \
            ut2 += fmaf(tt, fmaf(tt, fmaf(tt, c2.w, c2.z), c2.y), c2.x);    \
        }

    #pragma unroll 1
    for (int g = 0; g < 3; ++g) {
        ut0 = 0.f; ut1 = 0.f; ut2 = 0.f;
        int base = g << 5;
        #pragma unroll 8
        for (int p = 0; p < 32; ++p) PAIR_BODY(base + p)
        us0 += (double)ut0; us1 += (double)ut1; us2 += (double)ut2;
    }
    {
        ut0 = 0.f; ut1 = 0.f; ut2 = 0.f;
        #pragma unroll 8
        for (int p = 96; p < 127; ++p) PAIR_BODY(p)
        us0 += (double)ut0; us1 += (double)ut1; us2 += (double)ut2;
    }
    #undef PAIR_BODY

    // per-atom epilogue (wave-local, double precision for h/pre path)
    double wf0, wf1, wf2;
    {
        epid[wave][lane] = us0;
        double acc = 0.0;
        for (int m = 0; m < 64; ++m) acc += epid[wave][m] * (double)W2a[m*64 + f];
        wf0 = 1.0 + acc + 127.0 * (double)b2a[f];

        epid[wave][lane] = us1;
        double acc1 = 0.0;
        for (int m = 0; m < 64; ++m) acc1 += epid[wave][m] * (double)W2b[m*64 + f];
        wf1 = 1.0 + acc1 + 127.0 * (double)b2b[f];

        epid[wave][lane] = us2;
        double acc2 = 0.0;
        for (int m = 0; m < 64; ++m) acc2 += epid[wave][m] * (double)W2c[m*64 + f];
        wf2 = 1.0 + acc2 + 127.0 * (double)b2c[f];
    }
    double h0 = (double)Wenc[f] + (double)benc[f];
    double h  = h0 * wf0 * wf1 * wf2;
    epid[wave][lane] = h;
    double pre = (double)bt1[lane];
    for (int m = 0; m < 64; ++m) pre += epid[wave][m] * (double)Wt1[m*64 + lane];
    double tv = tanh(pre);
    float gv = (float)((1.0 - tv * tv) * (double)Wt2[lane]);

    float p1 = (float)(h0 * wf1 * wf2);
    float p2 = (float)(h0 * wf0 * wf2);
    float p3 = (float)(h0 * wf0 * wf1);

    epif[wave][lane] = gv;
    float dv = 0.f;
    for (int m = 0; m < 64; ++m) dv = fmaf(epif[wave][m], Wt1[lane*64 + m], dv);

    float* co = Cout + atom * 192;
    epif[wave][lane] = dv * p1;
    float c0 = 0.f;
    for (int m = 0; m < 64; ++m) c0 = fmaf(epif[wave][m], W2a[lane*64 + m], c0);
    co[lane] = c0;

    epif[wave][lane] = dv * p2;
    float c1 = 0.f;
    for (int m = 0; m < 64; ++m) c1 = fmaf(epif[wave][m], W2b[lane*64 + m], c1);
    co[64 + lane] = c1;

    epif[wave][lane] = dv * p3;
    float c2 = 0.f;
    for (int m = 0; m < 64; ++m) c2 = fmaf(epif[wave][m], W2c[lane*64 + m], c2);
    co[128 + lane] = c2;
}

// ------- backward via derivative coefficient table, d-row in LDS -------
__global__ __launch_bounds__(256) void k_bwd(
    const float* __restrict__ dws, const float4* __restrict__ B4,
    const float* __restrict__ C, float* __restrict__ T)
{
    __shared__ float dsh[4][128];
    int tid = threadIdx.x;
    int wave = tid >> 6, lane = tid & 63;
    int atom = blockIdx.x * 4 + wave;
    int b = atom >> 7, i = atom & 127;
    const float* drow = dws + (atom << 7);
    dsh[wave][lane]      = drow[lane];
    dsh[wave][64 + lane] = drow[64 + lane];
    const float* ci = C + atom * 192;
    float ci0 = ci[lane], ci1 = ci[64 + lane], ci2 = ci[128 + lane];
    float* Tb = T + ((size_t)b << 14);
    const float invh = (float)NI / 10.0f;
    float vm = 0.f;

    #pragma unroll 1
    for (int g = 0; g < 16; ++g) {
        int offb = 1 + (g << 2);
        float tt[4], cA[4], cB[4], cC[4];
        float4 u0[4], u1[4], u2[4];
        #pragma unroll
        for (int p = 0; p < 4; ++p) {
            int aa = (i + offb + p) & 127;
            float d = dsh[wave][aa];
            float fd = fminf(d * invh, (float)NI - 0.001f);
            float jf = floorf(fd);
            tt[p] = fd - jf;
            int j4 = (int)jf * 64 + lane;
            u0[p] = B4[j4];
            u1[p] = B4[NI * 64 + j4];
            u2[p] = B4[2 * NI * 64 + j4];
            const float* ca = C + (((b << 7) + aa) * 192);
            cA[p] = ca[lane]; cB[p] = ca[64 + lane]; cC[p] = ca[128 + lane];
        }
        #pragma unroll
        for (int p = 0; p < 4; ++p) {
            float t1 = tt[p];
            float g0 = fmaf(t1, fmaf(t1, fmaf(t1, u0[p].w, u0[p].z), u0[p].y), u0[p].x);
            float g1 = fmaf(t1, fmaf(t1, fmaf(t1, u1[p].w, u1[p].z), u1[p].y), u1[p].x);
            float g2 = fmaf(t1, fmaf(t1, fmaf(t1, u2[p].w, u2[p].z), u2[p].y), u2[p].x);
            float red = (ci0 + cA[p]) * g0 + (ci1 + cB[p]) * g1 + (ci2 + cC[p]) * g2;
            #pragma unroll
            for (int o = 1; o < 64; o <<= 1) red += __shfl_xor(red, o);
            if (lane == (g << 2) + p) vm = red;
        }
    }
    int off = lane + 1;
    if (off < 64 || i < 64) {
        int a = (i + off) & 127;
        Tb[(i << 7) + a] = vm;
        Tb[(a << 7) + i] = vm;
    }
}

__global__ __launch_bounds__(256) void k_force(
    const float* __restrict__ xs, const float* __restrict__ dws,
    const float* __restrict__ T, float* __restrict__ Fr)
{
    int tid = threadIdx.x;
    int wave = tid >> 6, lane = tid & 63;
    int atom = blockIdx.x * 4 + wave;
    int i = atom & 127;
    int b = atom >> 7;
    const float* xb = xs + b * (NN * 3);
    float xi0 = xb[i*3], xi1 = xb[i*3+1], xi2 = xb[i*3+2];
    const float* drow = dws + (atom << 7);
    const float* trow = T + (atom << 7);
    float fx = 0.f, fy = 0.f, fz = 0.f;
    for (int it = lane; it < 127; it += 64) {
        int aa = (i + 1 + it) & 127;
        float coef = trow[aa] / drow[aa];
        fx += coef * (xi0 - xb[aa*3]);
        fy += coef * (xi1 - xb[aa*3+1]);
        fz += coef * (xi2 - xb[aa*3+2]);
    }
    #pragma unroll
    for (int off = 1; off < 64; off <<= 1) {
        fx += __shfl_xor(fx, off);
        fy += __shfl_xor(fy, off);
        fz += __shfl_xor(fz, off);
    }
    if (lane == 0) {
        Fr[atom*3]   = fx;
        Fr[atom*3+1] = fy;
        Fr[atom*3+2] = fz;
    }
}

__global__ __launch_bounds__(128) void k_out(const float* __restrict__ Fr, float* __restrict__ out)
{
    __shared__ float rs[3][128];
    int b = blockIdx.x, n = threadIdx.x;
    float g0 = Fr[(b*128+n)*3], g1 = Fr[(b*128+n)*3+1], g2 = Fr[(b*128+n)*3+2];
    rs[0][n] = g0; rs[1][n] = g1; rs[2][n] = g2;
    __syncthreads();
    for (int s = 64; s > 0; s >>= 1) {
        if (n < s) {
            rs[0][n] += rs[0][n+s];
            rs[1][n] += rs[1][n+s];
            rs[2][n] += rs[2][n+s];
        }
        __syncthreads();
    }
    float m0 = rs[0][0] * (1.f/128.f);
    float m1 = rs[1][0] * (1.f/128.f);
    float m2 = rs[2][0] * (1.f/128.f);
    out[b*384 + n*3 + 0] = m0 - g0;
    out[b*384 + n*3 + 1] = m1 - g1;
    out[b*384 + n*3 + 2] = m2 - g2;
}

extern "C" void kernel_launch(void* const* d_in, const int* in_sizes, int n_in,
                              void* d_out, int out_size, void* d_ws, size_t ws_size,
                              hipStream_t stream)
{
    const float* xs   = (const float*)d_in[1];
    const float* mus  = (const float*)d_in[2];
    const float* gam  = (const float*)d_in[3];
    const float* Wenc = (const float*)d_in[4];
    const float* benc = (const float*)d_in[5];
    const float* W1a  = (const float*)d_in[6];
    const float* b1a  = (const float*)d_in[7];
    const float* W2a  = (const float*)d_in[8];
    const float* b2a  = (const float*)d_in[9];
    const float* W1b  = (const float*)d_in[10];
    const float* b1b  = (const float*)d_in[11];
    const float* W2b  = (const float*)d_in[12];
    const float* b2b  = (const float*)d_in[13];
    const float* W1c  = (const float*)d_in[14];
    const float* b1c  = (const float*)d_in[15];
    const float* W2c  = (const float*)d_in[16];
    const float* b2c  = (const float*)d_in[17];
    const float* Wt1  = (const float*)d_in[18];
    const float* bt1  = (const float*)d_in[19];
    const float* Wt2  = (const float*)d_in[20];

    float* ws  = (float*)d_ws;
    float* dws = ws;
    float* T   = ws + 524288;
    float4* A4 = (float4*)(ws + 1048576);
    float4* B4 = (float4*)(ws + 1540096);
    float* C   = ws + 2097152;
    float* Fr  = ws + 2883584;
    float* out = (float*)d_out;

    k_dt   <<<2208, 256, 0, stream>>>(xs, dws, W1a, W1b, W1c, b1a, b1b, b1c,
                                      mus, gam, A4, B4);
    k_fwd  <<<1024, 256, 0, stream>>>(dws, A4, W2a, W2b, W2c, b2a, b2b, b2c,
                                      Wenc, benc, Wt1, bt1, Wt2, C);
    k_bwd  <<<1024, 256, 0, stream>>>(dws, B4, C, T);
    k_force<<<1024, 256, 0, stream>>>(xs, dws, T, Fr);
    k_out  <<<32, 128, 0, stream>>>(Fr, out);
}